// Round 2
// baseline (568.261 us; speedup 1.0000x reference)
//
#include <hip/hip_runtime.h>

#define T_LEN 2048
#define C_DIM 1024
#define PAIR_F 768          // floats per (head, step-pair) packet
#define BPAIR 4             // pairs per vscan LDS batch
#define BATCH_F (BPAIR * PAIR_F)   // 3072 floats, contiguous per batch

#define AS1 __attribute__((address_space(1)))
#define AS3 __attribute__((address_space(3)))
#define VM_FENCE0() asm volatile("s_waitcnt vmcnt(0)" ::: "memory")
#define C_FENCE() asm volatile("" ::: "memory")

typedef __attribute__((ext_vector_type(8))) short bf8_t;
typedef __attribute__((ext_vector_type(4))) float f4_t;

static __device__ __forceinline__ float sigf(float x) {
    return 1.f / (1.f + __expf(-x));
}
static __device__ __forceinline__ unsigned short f2bf(float f) {
    unsigned u = __float_as_uint(f);
    u += 0x7fff + ((u >> 16) & 1);
    return (unsigned short)(u >> 16);
}

// ---------------------------------------------------------------------------
// Convert the four 1024x1024 fp32 weights into one bf16 block (1M strides),
// plus the transposed LoRA stage-1 weights (blocks 4096..4383).
// lw16 layout: w1t[64][1024] | a1t[64][1024] | v1t[64][1024] | g1t[128][1024]
// ---------------------------------------------------------------------------
__global__ __launch_bounds__(256) void wcvtall(
    const float* __restrict__ Wr, const float* __restrict__ Wk,
    const float* __restrict__ Wv, const float* __restrict__ Wo,
    const float* __restrict__ w1, const float* __restrict__ a1,
    const float* __restrict__ v1, const float* __restrict__ g1,
    unsigned short* __restrict__ dst, unsigned short* __restrict__ lw16)
{
    const int b = blockIdx.x;
    if (b < 4096) {
        const size_t idx = ((size_t)b * 256 + threadIdx.x) * 4;
        const int sel = (int)(idx >> 20);
        const float* src = sel == 0 ? Wr : sel == 1 ? Wk : sel == 2 ? Wv : Wo;
        float4 v = *(const float4*)(src + (idx & 0xFFFFF));
        ushort4 o = {f2bf(v.x), f2bf(v.y), f2bf(v.z), f2bf(v.w)};
        *(ushort4*)(dst + idx) = o;
        return;
    }
    const int row = b - 4096;         // 0..287
    const float* src; int Kh, i; unsigned short* dl;
    if (row < 64)       { src = w1; Kh = 64;  i = row;       dl = lw16 + (size_t)row * 1024; }
    else if (row < 128) { src = a1; Kh = 64;  i = row - 64;  dl = lw16 + (size_t)row * 1024; }
    else if (row < 160) { src = v1; Kh = 32;  i = row - 128; dl = lw16 + (size_t)(row - 128 + 128) * 1024; }
    else                { src = g1; Kh = 128; i = row - 160; dl = lw16 + (size_t)(row - 160 + 192) * 1024; }
    const int c0 = threadIdx.x * 4;
#pragma unroll
    for (int u = 0; u < 4; ++u)
        dl[c0 + u] = f2bf(src[(size_t)(c0 + u) * Kh + i]);
}

// ---------------------------------------------------------------------------
// Token-shift mix -> bf16 A-matrices for r/k/v projections and w/a/g LoRA.
// ---------------------------------------------------------------------------
__global__ __launch_bounds__(256) void xcvt(
    const float* __restrict__ x, const float* __restrict__ xprev,
    const float* __restrict__ x_r, const float* __restrict__ x_k,
    const float* __restrict__ x_v, const float* __restrict__ x_w,
    const float* __restrict__ x_a, const float* __restrict__ x_g,
    unsigned short* __restrict__ xr16, unsigned short* __restrict__ xk16,
    unsigned short* __restrict__ xv16, unsigned short* __restrict__ xw16,
    unsigned short* __restrict__ xa16, unsigned short* __restrict__ xg16)
{
    const int t = blockIdx.x;
    const int c0 = threadIdx.x * 4;
    const size_t base = (size_t)t * C_DIM + c0;
    float4 xv = *(const float4*)(x + base);
    float4 pv = (t == 0) ? *(const float4*)(xprev + c0)
                         : *(const float4*)(x + base - C_DIM);
    float4 dx = {pv.x - xv.x, pv.y - xv.y, pv.z - xv.z, pv.w - xv.w};
#define MIXOUT(mixp, dstp)                                                    \
    {                                                                          \
        float4 mv = *(const float4*)(mixp + c0);                               \
        ushort4 o = {f2bf(xv.x + dx.x * mv.x), f2bf(xv.y + dx.y * mv.y),       \
                     f2bf(xv.z + dx.z * mv.z), f2bf(xv.w + dx.w * mv.w)};      \
        *(ushort4*)(dstp + base) = o;                                          \
    }
    MIXOUT(x_r, xr16) MIXOUT(x_k, xk16) MIXOUT(x_v, xv16)
    MIXOUT(x_w, xw16) MIXOUT(x_a, xa16) MIXOUT(x_g, xg16)
#undef MIXOUT
}

// ---------------------------------------------------------------------------
// bf16 MFMA NT GEMM core: out[t,i] = sum_c A[t,c]*W[i,c], fp32 accumulate.
// ---------------------------------------------------------------------------
static __device__ __forceinline__ void gemm_core(
    const unsigned short* __restrict__ A, const unsigned short* __restrict__ W,
    float* __restrict__ out)
{
    __shared__ unsigned short Ab[2][128 * 32];
    __shared__ unsigned short Bb[2][64 * 32];
    const int tid = threadIdx.x;
    const int lane = tid & 63;
    const int w = tid >> 6;
    const int n0 = blockIdx.x * 64;
    const int t0 = blockIdx.y * 128;
    const int wm = (w & 1) * 64;
    const int wn = (w >> 1) * 32;
    const int srow = lane >> 2;
    const int scol = (lane & 3) * 8;

    f4_t acc[4][2];
#pragma unroll
    for (int i = 0; i < 4; ++i)
#pragma unroll
        for (int j = 0; j < 2; ++j)
            acc[i][j] = (f4_t){0.f, 0.f, 0.f, 0.f};

#pragma unroll
    for (int s = 0; s < 2; ++s) {
        const int i = 2 * w + s;
        __builtin_amdgcn_global_load_lds(
            (const AS1 unsigned int*)(A + (size_t)(t0 + i * 16 + srow) * 1024 + scol),
            (AS3 unsigned int*)(&Ab[0][i * 512 + lane * 8]), 16, 0, 0);
    }
    __builtin_amdgcn_global_load_lds(
        (const AS1 unsigned int*)(W + (size_t)(n0 + w * 16 + srow) * 1024 + scol),
        (AS3 unsigned int*)(&Bb[0][w * 512 + lane * 8]), 16, 0, 0);

    const int mrow = lane & 15;
    const int kq = (lane >> 4) * 8;
    for (int k0 = 0; k0 < 1024; k0 += 32) {
        const int cur = (k0 >> 5) & 1, nxt = cur ^ 1;
        __syncthreads();
        if (k0 + 32 < 1024) {
            const int k1 = k0 + 32;
#pragma unroll
            for (int s = 0; s < 2; ++s) {
                const int i = 2 * w + s;
                __builtin_amdgcn_global_load_lds(
                    (const AS1 unsigned int*)(A + (size_t)(t0 + i * 16 + srow) * 1024 + k1 + scol),
                    (AS3 unsigned int*)(&Ab[nxt][i * 512 + lane * 8]), 16, 0, 0);
            }
            __builtin_amdgcn_global_load_lds(
                (const AS1 unsigned int*)(W + (size_t)(n0 + w * 16 + srow) * 1024 + k1 + scol),
                (AS3 unsigned int*)(&Bb[nxt][w * 512 + lane * 8]), 16, 0, 0);
        }
        bf8_t af[4], bfr[2];
#pragma unroll
        for (int i = 0; i < 4; ++i)
            af[i] = *(const bf8_t*)(&Ab[cur][(wm + 16 * i + mrow) * 32 + kq]);
#pragma unroll
        for (int j = 0; j < 2; ++j)
            bfr[j] = *(const bf8_t*)(&Bb[cur][(wn + 16 * j + mrow) * 32 + kq]);
#pragma unroll
        for (int i = 0; i < 4; ++i)
#pragma unroll
            for (int j = 0; j < 2; ++j)
                acc[i][j] = __builtin_amdgcn_mfma_f32_16x16x32_bf16(
                    af[i], bfr[j], acc[i][j], 0, 0, 0);
    }
    const int crow = (lane >> 4) * 4;
    const int ccol = lane & 15;
#pragma unroll
    for (int i = 0; i < 4; ++i)
#pragma unroll
        for (int j = 0; j < 2; ++j)
#pragma unroll
            for (int u = 0; u < 4; ++u)
                out[(size_t)(t0 + wm + 16 * i + crow + u) * 1024
                    + n0 + wn + 16 * j + ccol] = acc[i][j][u];
}

__global__ __launch_bounds__(256) void gemm_bf16_3(
    const unsigned short* __restrict__ xr, const unsigned short* __restrict__ xk,
    const unsigned short* __restrict__ xv,
    const unsigned short* __restrict__ Wr, const unsigned short* __restrict__ Wk,
    const unsigned short* __restrict__ Wv,
    float* __restrict__ rB, float* __restrict__ kB, float* __restrict__ vB)
{
    const int z = blockIdx.z;
    const unsigned short* A = z == 0 ? xr : z == 1 ? xk : xv;
    const unsigned short* W = z == 0 ? Wr : z == 1 ? Wk : Wv;
    float* out = z == 0 ? rB : z == 1 ? kB : vB;
    gemm_core(A, W, out);
}

__global__ __launch_bounds__(256) void gemm_bf16(
    const unsigned short* __restrict__ A, const unsigned short* __restrict__ W,
    float* __restrict__ out)
{
    gemm_core(A, W, out);
}

// ---------------------------------------------------------------------------
// Fused LoRA stage-1 via MFMA: z = 0:w(tanh,N=64) 1:a(N=64) 2:v(N=32) 3:g(sig,N=128)
// ---------------------------------------------------------------------------
__global__ __launch_bounds__(256) void lora1m(
    const unsigned short* __restrict__ xw, const unsigned short* __restrict__ xa,
    const unsigned short* __restrict__ xv, const unsigned short* __restrict__ xg,
    const unsigned short* __restrict__ lw16,
    float* __restrict__ hw, float* __restrict__ ha, float* __restrict__ hv,
    float* __restrict__ hg)
{
    const int z = blockIdx.z;
    const unsigned short* A = z == 0 ? xw : z == 1 ? xa : z == 2 ? xv : xg;
    const unsigned short* W = lw16 + (size_t)(z == 0 ? 0 : z == 1 ? 64 : z == 2 ? 128 : 192) * 1024;
    float* out = z == 0 ? hw : z == 1 ? ha : z == 2 ? hv : hg;
    const int N  = z == 3 ? 128 : z == 2 ? 32 : 64;
    const int Ns = z == 3 ? 128 : 64;
    const int n0 = blockIdx.x * 64;
    if (n0 >= Ns) return;

    __shared__ unsigned short Ab[2][128 * 32];
    __shared__ unsigned short Bb[2][64 * 32];
    const int tid = threadIdx.x;
    const int lane = tid & 63;
    const int w = tid >> 6;
    const int t0 = blockIdx.y * 128;
    const int wm = (w & 1) * 64;
    const int wn = (w >> 1) * 32;
    const int srow = lane >> 2;
    const int scol = (lane & 3) * 8;

    f4_t acc[4][2];
#pragma unroll
    for (int i = 0; i < 4; ++i)
#pragma unroll
        for (int j = 0; j < 2; ++j)
            acc[i][j] = (f4_t){0.f, 0.f, 0.f, 0.f};

#pragma unroll
    for (int s = 0; s < 2; ++s) {
        const int i = 2 * w + s;
        __builtin_amdgcn_global_load_lds(
            (const AS1 unsigned int*)(A + (size_t)(t0 + i * 16 + srow) * 1024 + scol),
            (AS3 unsigned int*)(&Ab[0][i * 512 + lane * 8]), 16, 0, 0);
    }
    __builtin_amdgcn_global_load_lds(
        (const AS1 unsigned int*)(W + (size_t)(n0 + w * 16 + srow) * 1024 + scol),
        (AS3 unsigned int*)(&Bb[0][w * 512 + lane * 8]), 16, 0, 0);

    const int mrow = lane & 15;
    const int kq = (lane >> 4) * 8;
    for (int k0 = 0; k0 < 1024; k0 += 32) {
        const int cur = (k0 >> 5) & 1, nxt = cur ^ 1;
        __syncthreads();
        if (k0 + 32 < 1024) {
            const int k1 = k0 + 32;
#pragma unroll
            for (int s = 0; s < 2; ++s) {
                const int i = 2 * w + s;
                __builtin_amdgcn_global_load_lds(
                    (const AS1 unsigned int*)(A + (size_t)(t0 + i * 16 + srow) * 1024 + k1 + scol),
                    (AS3 unsigned int*)(&Ab[nxt][i * 512 + lane * 8]), 16, 0, 0);
            }
            __builtin_amdgcn_global_load_lds(
                (const AS1 unsigned int*)(W + (size_t)(n0 + w * 16 + srow) * 1024 + k1 + scol),
                (AS3 unsigned int*)(&Bb[nxt][w * 512 + lane * 8]), 16, 0, 0);
        }
        bf8_t af[4], bfr[2];
#pragma unroll
        for (int i = 0; i < 4; ++i)
            af[i] = *(const bf8_t*)(&Ab[cur][(wm + 16 * i + mrow) * 32 + kq]);
#pragma unroll
        for (int j = 0; j < 2; ++j)
            bfr[j] = *(const bf8_t*)(&Bb[cur][(wn + 16 * j + mrow) * 32 + kq]);
#pragma unroll
        for (int i = 0; i < 4; ++i)
#pragma unroll
            for (int j = 0; j < 2; ++j)
                acc[i][j] = __builtin_amdgcn_mfma_f32_16x16x32_bf16(
                    af[i], bfr[j], acc[i][j], 0, 0, 0);
    }
    const int crow = (lane >> 4) * 4;
    const int ccol = lane & 15;
#pragma unroll
    for (int i = 0; i < 4; ++i)
#pragma unroll
        for (int j = 0; j < 2; ++j) {
            const int col = n0 + wn + 16 * j + ccol;
            if (col < N) {
#pragma unroll
                for (int u = 0; u < 4; ++u) {
                    float vv = acc[i][j][u];
                    if (z == 0) vv = tanhf(vv);
                    else if (z == 3) vv = sigf(vv);
                    out[(size_t)(t0 + wm + 16 * i + crow + u) * N + col] = vv;
                }
            }
        }
}

// ---------------------------------------------------------------------------
// Fused LoRA-2 (w/a/v/g) + k post-process + PAIR-COMPOSED packet packing.
// Block = 16 tokens x 256 channels; head = 64 consecutive channels = 1 wave.
// Per step-pair packet (768 floats):
//   E=e1e2 @0 | A1=aa1 @64 | A2e=e1*aa2 @128 | B1e=bb1*e2 @192 | K1e=k1*e2 @256
//   | B2=bb2 @320 | K2=k2 @384 | R1e=e1*r1 @448 | R2=r2 @512 | V1 @576 | V2 @640
//   | scalars @704: cba=bb1.aa2, cka=k1.aa2, cbr=bb1.r1, ckr=k1.r1
// ---------------------------------------------------------------------------
__global__ __launch_bounds__(256) void lora2f(
    const float* __restrict__ hwB, const float* __restrict__ haB,
    const float* __restrict__ hvB, const float* __restrict__ hgB,
    const float* __restrict__ w2, const float* __restrict__ a2,
    const float* __restrict__ v2, const float* __restrict__ g2,
    const float* __restrict__ w0, const float* __restrict__ a0,
    const float* __restrict__ v0,
    const float* __restrict__ k_k, const float* __restrict__ k_a,
    const float* __restrict__ v_first, const float* __restrict__ rB,
    float* __restrict__ kB, float* __restrict__ vB, float* __restrict__ gB,
    float* __restrict__ pk)
{
    __shared__ __align__(16) float hsW[16 * 64], hsA[16 * 64];
    __shared__ __align__(16) float hsV[16 * 32], hsG[16 * 128];
    const int tid = threadIdx.x;
    const int t0 = blockIdx.y * 16;
    const int i  = blockIdx.x * 256 + tid;
    const int h  = i >> 6;
    const int j  = i & 63;
    for (int idx = tid; idx < 16 * 64; idx += 256) {
        hsW[idx] = hwB[(size_t)t0 * 64 + idx];
        hsA[idx] = haB[(size_t)t0 * 64 + idx];
    }
    for (int idx = tid; idx < 16 * 32; idx += 256)
        hsV[idx] = hvB[(size_t)t0 * 32 + idx];
    for (int idx = tid; idx < 16 * 128; idx += 256)
        hsG[idx] = hgB[(size_t)t0 * 128 + idx];
    __syncthreads();

    float av[16], ew[16], vf[16];
    { // a = sigmoid(a0 + ha@a2)
        float acc[16];
        const float b0 = a0[i];
#pragma unroll
        for (int tt = 0; tt < 16; ++tt) acc[tt] = b0;
        for (int jj = 0; jj < 64; jj += 4) {
            const float q0 = a2[(size_t)(jj + 0) * C_DIM + i];
            const float q1 = a2[(size_t)(jj + 1) * C_DIM + i];
            const float q2 = a2[(size_t)(jj + 2) * C_DIM + i];
            const float q3 = a2[(size_t)(jj + 3) * C_DIM + i];
#pragma unroll
            for (int tt = 0; tt < 16; ++tt) {
                float4 h4 = *(const float4*)(hsA + tt * 64 + jj);
                acc[tt] = fmaf(h4.x, q0, acc[tt]);
                acc[tt] = fmaf(h4.y, q1, acc[tt]);
                acc[tt] = fmaf(h4.z, q2, acc[tt]);
                acc[tt] = fmaf(h4.w, q3, acc[tt]);
            }
        }
#pragma unroll
        for (int tt = 0; tt < 16; ++tt) av[tt] = sigf(acc[tt]);
    }
    { // exp(w)
        float acc[16];
        const float b0 = w0[i];
#pragma unroll
        for (int tt = 0; tt < 16; ++tt) acc[tt] = b0;
        for (int jj = 0; jj < 64; jj += 4) {
            const float q0 = w2[(size_t)(jj + 0) * C_DIM + i];
            const float q1 = w2[(size_t)(jj + 1) * C_DIM + i];
            const float q2 = w2[(size_t)(jj + 2) * C_DIM + i];
            const float q3 = w2[(size_t)(jj + 3) * C_DIM + i];
#pragma unroll
            for (int tt = 0; tt < 16; ++tt) {
                float4 h4 = *(const float4*)(hsW + tt * 64 + jj);
                acc[tt] = fmaf(h4.x, q0, acc[tt]);
                acc[tt] = fmaf(h4.y, q1, acc[tt]);
                acc[tt] = fmaf(h4.z, q2, acc[tt]);
                acc[tt] = fmaf(h4.w, q3, acc[tt]);
            }
        }
#pragma unroll
        for (int tt = 0; tt < 16; ++tt)
            ew[tt] = __expf(-0.6065306597126334f * sigf(acc[tt]));
    }
    { // v mix
        float acc[16];
        const float b0 = v0[i];
#pragma unroll
        for (int tt = 0; tt < 16; ++tt) acc[tt] = b0;
        for (int jj = 0; jj < 32; jj += 4) {
            const float q0 = v2[(size_t)(jj + 0) * C_DIM + i];
            const float q1 = v2[(size_t)(jj + 1) * C_DIM + i];
            const float q2 = v2[(size_t)(jj + 2) * C_DIM + i];
            const float q3 = v2[(size_t)(jj + 3) * C_DIM + i];
#pragma unroll
            for (int tt = 0; tt < 16; ++tt) {
                float4 h4 = *(const float4*)(hsV + tt * 32 + jj);
                acc[tt] = fmaf(h4.x, q0, acc[tt]);
                acc[tt] = fmaf(h4.y, q1, acc[tt]);
                acc[tt] = fmaf(h4.z, q2, acc[tt]);
                acc[tt] = fmaf(h4.w, q3, acc[tt]);
            }
        }
#pragma unroll
        for (int tt = 0; tt < 16; ++tt) {
            const size_t gi = (size_t)(t0 + tt) * C_DIM + i;
            const float s = sigf(acc[tt]);
            const float vr = vB[gi];
            vf[tt] = vr + (v_first[gi] - vr) * s;
            vB[gi] = vf[tt];
        }
    }
    { // g
        float acc[16];
#pragma unroll
        for (int tt = 0; tt < 16; ++tt) acc[tt] = 0.f;
        for (int jj = 0; jj < 128; jj += 4) {
            const float q0 = g2[(size_t)(jj + 0) * C_DIM + i];
            const float q1 = g2[(size_t)(jj + 1) * C_DIM + i];
            const float q2 = g2[(size_t)(jj + 2) * C_DIM + i];
            const float q3 = g2[(size_t)(jj + 3) * C_DIM + i];
#pragma unroll
            for (int tt = 0; tt < 16; ++tt) {
                float4 h4 = *(const float4*)(hsG + tt * 128 + jj);
                acc[tt] = fmaf(h4.x, q0, acc[tt]);
                acc[tt] = fmaf(h4.y, q1, acc[tt]);
                acc[tt] = fmaf(h4.z, q2, acc[tt]);
                acc[tt] = fmaf(h4.w, q3, acc[tt]);
            }
        }
#pragma unroll
        for (int tt = 0; tt < 16; ++tt)
            gB[(size_t)(t0 + tt) * C_DIM + i] = acc[tt];
    }
    // k post-process + pair-composed packing
    const float kkw = k_k[i], kaw = k_a[i];
    const size_t pbase = (size_t)h * 1024 * PAIR_F;
    for (int pt = 0; pt < 8; ++pt) {
        const int tt1 = 2 * pt, tt2 = 2 * pt + 1;
        float r_[2], e_[2], kf_[2], v_[2], aa_[2], bb_[2];
#pragma unroll
        for (int u = 0; u < 2; ++u) {
            const int tt = 2 * pt + u;
            const size_t gi = (size_t)(t0 + tt) * C_DIM + i;
            const float kraw = kB[gi];
            const float kn = kraw * kkw;
            float ss = kn * kn;
#pragma unroll
            for (int m = 1; m <= 32; m <<= 1) ss += __shfl_xor(ss, m);
            const float sc = 1.f / fmaxf(sqrtf(ss), 1e-12f);
            const float kk = kn * sc;
            const float a_ = av[tt];
            const float kf = kraw * (1.f + (a_ - 1.f) * kaw);
            kB[gi] = kf;
            r_[u] = rB[gi];
            e_[u] = ew[tt];
            kf_[u] = kf;
            v_[u] = vf[tt];
            aa_[u] = -kk;
            bb_[u] = kk * a_;
        }
        (void)tt1; (void)tt2;
        const float E   = e_[0] * e_[1];
        const float A2e = e_[0] * aa_[1];
        const float B1e = bb_[0] * e_[1];
        const float K1e = kf_[0] * e_[1];
        const float R1e = e_[0] * r_[0];
        float cba = bb_[0] * aa_[1];
        float cka = kf_[0] * aa_[1];
        float cbr = bb_[0] * r_[0];
        float ckr = kf_[0] * r_[0];
#pragma unroll
        for (int m = 1; m <= 32; m <<= 1) {
            cba += __shfl_xor(cba, m);
            cka += __shfl_xor(cka, m);
            cbr += __shfl_xor(cbr, m);
            ckr += __shfl_xor(ckr, m);
        }
        float* p = pk + pbase + (size_t)(blockIdx.y * 8 + pt) * PAIR_F;
        p[j]        = E;
        p[64 + j]   = aa_[0];
        p[128 + j]  = A2e;
        p[192 + j]  = B1e;
        p[256 + j]  = K1e;
        p[320 + j]  = bb_[1];
        p[384 + j]  = kf_[1];
        p[448 + j]  = R1e;
        p[512 + j]  = r_[1];
        p[576 + j]  = v_[0];
        p[640 + j]  = v_[1];
        if (j == 0) {
            p[704] = cba; p[705] = cka; p[706] = cbr; p[707] = ckr;
        }
    }
}

// ---------------------------------------------------------------------------
// v-row-parallel scan over step-PAIRS. 256 blocks x 64 threads; block b ->
// head (b&15). Per pair: 3 independent reductions (u1,u2,o1) from S_t, scalar
// fixups, 5-term update, then o2 (overlaps next pair's partials).
//
// QUAD-buffered LDS: 3 batches of global_load_lds in flight (prefetch
// distance ~3 batch-computes) so HBM/L3 round-trip (~900-2500cy) hides
// under compute. Steady-state fence vmcnt(32): issue-order trace shows
// outstanding at fence = L(b+1)12 + L(b+2)12 + L(b+3)12 + S(b)8 + S(b-1)8
// = 52 -> waiting to 32 completes exactly L(b+1) + S(b-1). Tail (last 3
// batches, nothing left to issue) drains with vmcnt(0) - loads are ancient.
// sched_barrier(0) pins pair_read(s+1) before pair_compute(s) (r1: killed
// all LDS bank conflicts).
// ---------------------------------------------------------------------------
struct Pair {
    float4 E, A1, A2e, B1e, K1e, B2, K2, R1e, R2;
    float v1, v2;
    float4 sc;   // cba, cka, cbr, ckr
};

static __device__ __forceinline__ float red16(float x) {
    int xi;
    xi = __builtin_amdgcn_mov_dpp(__float_as_int(x), 0x128, 0xf, 0xf, true);
    x += __int_as_float(xi);
    xi = __builtin_amdgcn_mov_dpp(__float_as_int(x), 0x124, 0xf, 0xf, true);
    x += __int_as_float(xi);
    xi = __builtin_amdgcn_mov_dpp(__float_as_int(x), 0x122, 0xf, 0xf, true);
    x += __int_as_float(xi);
    xi = __builtin_amdgcn_mov_dpp(__float_as_int(x), 0x121, 0xf, 0xf, true);
    x += __int_as_float(xi);
    return x;
}

static __device__ __forceinline__ float dot4(const float4& S, const float4& A) {
    // two parallel 2-chains + combine: entry latency ~12cy instead of 16cy
    float d0 = S.x * A.x;
    float d1 = S.y * A.y;
    d0 = fmaf(S.z, A.z, d0);
    d1 = fmaf(S.w, A.w, d1);
    return d0 + d1;
}

static __device__ __forceinline__ void issue_batch(
    const float* __restrict__ hbase, float* __restrict__ buf, int batch, int l)
{
    const float* src = hbase + (size_t)batch * BATCH_F;
#pragma unroll
    for (int i = 0; i < BATCH_F / 256; ++i)   // 12 full-wave 16B loads
        __builtin_amdgcn_global_load_lds(
            (const AS1 unsigned int*)(src + i * 256 + l * 4),
            (AS3 unsigned int*)(&buf[i * 256 + l * 4]), 16, 0, 0);
}

static __device__ __forceinline__ Pair pair_read(
    const float* __restrict__ buf, int s, int j0, int vidx)
{
    Pair P;
    const float* p = buf + s * PAIR_F;
    P.E   = *(const float4*)(p + j0);
    P.A1  = *(const float4*)(p + 64 + j0);
    P.A2e = *(const float4*)(p + 128 + j0);
    P.B1e = *(const float4*)(p + 192 + j0);
    P.K1e = *(const float4*)(p + 256 + j0);
    P.B2  = *(const float4*)(p + 320 + j0);
    P.K2  = *(const float4*)(p + 384 + j0);
    P.R1e = *(const float4*)(p + 448 + j0);
    P.R2  = *(const float4*)(p + 512 + j0);
    P.v1  = p[576 + vidx];
    P.v2  = p[640 + vidx];
    P.sc  = *(const float4*)(p + 704);
    return P;
}

static __device__ __forceinline__ void pair_compute(
    float4& S, const Pair& P, float* __restrict__ y,
    int pi, int cb, int vidx, int lane)
{
    const float u1 = red16(dot4(S, P.A1));
    const float u2 = red16(dot4(S, P.A2e));
    float o1       = red16(dot4(S, P.R1e));
    const float sa1 = u1;
    const float sa2 = fmaf(P.v1, P.sc.y, fmaf(sa1, P.sc.x, u2));
    o1 = fmaf(P.v1, P.sc.w, fmaf(sa1, P.sc.z, o1));
    if ((lane & 15) == 0)
        y[(size_t)(2 * pi) * C_DIM + cb + vidx] = o1;
    // S = S*E + sa1*B1e + v1*K1e + sa2*B2 + v2*K2  (tree'd)
    float ax, ay, az, aw, bx, by, bz, bw;
    ax = fmaf(sa1, P.B1e.x, S.x * P.E.x); bx = fmaf(sa2, P.B2.x, P.v1 * P.K1e.x);
    ay = fmaf(sa1, P.B1e.y, S.y * P.E.y); by = fmaf(sa2, P.B2.y, P.v1 * P.K1e.y);
    az = fmaf(sa1, P.B1e.z, S.z * P.E.z); bz = fmaf(sa2, P.B2.z, P.v1 * P.K1e.z);
    aw = fmaf(sa1, P.B1e.w, S.w * P.E.w); bw = fmaf(sa2, P.B2.w, P.v1 * P.K1e.w);
    S.x = fmaf(P.v2, P.K2.x, ax + bx);
    S.y = fmaf(P.v2, P.K2.y, ay + by);
    S.z = fmaf(P.v2, P.K2.z, az + bz);
    S.w = fmaf(P.v2, P.K2.w, aw + bw);
    const float o2 = red16(dot4(S, P.R2));
    if ((lane & 15) == 0)
        y[(size_t)(2 * pi + 1) * C_DIM + cb + vidx] = o2;
}

__global__ __launch_bounds__(64) void vscan(
    const float* __restrict__ pk, const float* __restrict__ init_state,
    float* __restrict__ y)
{
    const int h  = blockIdx.x & 15;     // b%8 == h%8 -> per-head XCD locality
    const int wv = blockIdx.x >> 4;
    const int l  = threadIdx.x;
    const int vidx = wv * 4 + (l >> 4);
    const int j0 = (l & 15) * 4;
    const int cb = h * 64;

    __shared__ __align__(16) float buf[4][BATCH_F];
    const float* hbase = pk + (size_t)h * 1024 * PAIR_F;

    float4 S = *(const float4*)(init_state + h * 4096 + vidx * 64 + j0);

    issue_batch(hbase, buf[0], 0, l);
    issue_batch(hbase, buf[1], 1, l);
    issue_batch(hbase, buf[2], 2, l);
    asm volatile("s_waitcnt vmcnt(24)" ::: "memory");   // batch 0 landed
    Pair cur = pair_read(buf[0], 0, j0, vidx);
    const int NB = 1024 / BPAIR;        // 256 batches
    for (int b = 0; b < NB; ++b) {
        if (b + 3 < NB)
            issue_batch(hbase, buf[(b + 3) & 3], b + 3, l);
        C_FENCE();                      // keep the 12 loads ahead of stores
        const float* cbuf = buf[b & 3];
#pragma unroll
        for (int s = 0; s < BPAIR; ++s) {
            Pair nxt;
            if (s + 1 < BPAIR) nxt = pair_read(cbuf, s + 1, j0, vidx);
            // Pin the pipeline: nxt's ds_reads are issued here and may NOT
            // sink into/past the compute of cur -> their latency overlaps
            // pair_compute(cur), results stay resident in VGPRs.
            __builtin_amdgcn_sched_barrier(0);
            pair_compute(S, cur, y, b * BPAIR + s, cb, vidx, l);
            if (s + 1 < BPAIR) cur = nxt;
        }
        if (b + 1 < NB) {
            if (b + 3 < NB) {
                // steady state: completes exactly L(b+1) (+ old stores)
                asm volatile("s_waitcnt vmcnt(32)" ::: "memory");
            } else {
                VM_FENCE0();            // tail: nothing new issued, drain
            }
            cur = pair_read(buf[(b + 1) & 3], 0, j0, vidx);
            __builtin_amdgcn_sched_barrier(0);
        }
    }
}

// ---------------------------------------------------------------------------
// GroupNorm + bonus + *g ; writes bf16 (xo*g) for the final MFMA GEMM.
// ---------------------------------------------------------------------------
__global__ __launch_bounds__(256) void gn_bonus(
    const float* __restrict__ y, const float* __restrict__ rb,
    const float* __restrict__ kb, const float* __restrict__ vb,
    const float* __restrict__ gb, const float* __restrict__ r_k,
    const float* __restrict__ lnw, const float* __restrict__ lnb,
    unsigned short* __restrict__ yg)
{
    const int t = blockIdx.x, tid = threadIdx.x;
    const int c0 = tid << 2;
    const size_t base = (size_t)t * C_DIM + c0;
    float4 yv = *(const float4*)(y + base);
    float sum = yv.x + yv.y + yv.z + yv.w;
    float ss  = yv.x * yv.x + yv.y * yv.y + yv.z * yv.z + yv.w * yv.w;
    float4 rv = *(const float4*)(rb + base);
    float4 kv = *(const float4*)(kb + base);
    float4 rkv = *(const float4*)(r_k + c0);
    float dot = rv.x * kv.x * rkv.x + rv.y * kv.y * rkv.y +
                rv.z * kv.z * rkv.z + rv.w * kv.w * rkv.w;
#pragma unroll
    for (int m = 1; m <= 8; m <<= 1) {
        sum += __shfl_xor(sum, m);
        ss  += __shfl_xor(ss, m);
        dot += __shfl_xor(dot, m);
    }
    const float mu = sum * 0.015625f;
    const float var = ss * 0.015625f - mu * mu;
    const float rstd = rsqrtf(var + 0.00064f);
    float4 wv = *(const float4*)(lnw + c0);
    float4 bv = *(const float4*)(lnb + c0);
    float4 vv = *(const float4*)(vb + base);
    float4 gv = *(const float4*)(gb + base);
    ushort4 o;
    o.x = f2bf(((yv.x - mu) * rstd * wv.x + bv.x + dot * vv.x) * gv.x);
    o.y = f2bf(((yv.y - mu) * rstd * wv.y + bv.y + dot * vv.y) * gv.y);
    o.z = f2bf(((yv.z - mu) * rstd * wv.z + bv.z + dot * vv.z) * gv.z);
    o.w = f2bf(((yv.w - mu) * rstd * wv.w + bv.w + dot * vv.w) * gv.w);
    *(ushort4*)(yg + base) = o;
}

// ---------------------------------------------------------------------------
extern "C" void kernel_launch(void* const* d_in, const int* in_sizes, int n_in,
                              void* d_out, int out_size, void* d_ws, size_t ws_size,
                              hipStream_t stream)
{
    (void)in_sizes; (void)n_in; (void)out_size; (void)ws_size;
    const float* x       = (const float*)d_in[0];
    const float* v_first = (const float*)d_in[1];
    const float* x_prev  = (const float*)d_in[2];
    const float* init_st = (const float*)d_in[3];
    const float* x_r = (const float*)d_in[4];
    const float* x_w = (const float*)d_in[5];
    const float* x_k = (const float*)d_in[6];
    const float* x_v = (const float*)d_in[7];
    const float* x_a = (const float*)d_in[8];
    const float* x_g = (const float*)d_in[9];
    const float* w0  = (const float*)d_in[10];
    const float* a0  = (const float*)d_in[11];
    const float* v0  = (const float*)d_in[12];
    const float* k_k = (const float*)d_in[13];
    const float* k_a = (const float*)d_in[14];
    const float* w1  = (const float*)d_in[15];
    const float* w2  = (const float*)d_in[16];
    const float* a1  = (const float*)d_in[17];
    const float* a2  = (const float*)d_in[18];
    const float* v1  = (const float*)d_in[19];
    const float* v2  = (const float*)d_in[20];
    const float* g1  = (const float*)d_in[21];
    const float* g2  = (const float*)d_in[22];
    const float* r_k = (const float*)d_in[23];
    const float* Wr  = (const float*)d_in[24];
    const float* Wk  = (const float*)d_in[25];
    const float* Wv  = (const float*)d_in[26];
    const float* Wo  = (const float*)d_in[27];
    const float* ln_w = (const float*)d_in[28];
    const float* ln_b = (const float*)d_in[29];

    float* out = (float*)d_out;
    float* ws  = (float*)d_ws;
    const size_t NE = (size_t)T_LEN * C_DIM;   // 2M
    const size_t WE = (size_t)C_DIM * C_DIM;   // 1M
    float* rB  = ws;
    float* kB  = ws + NE;
    float* vB  = ws + 2 * NE;
    float* gB  = ws + 3 * NE;
    float* hwB = ws + 4 * NE;                  // T*64
    float* haB = hwB + (size_t)T_LEN * 64;
    float* hvB = haB + (size_t)T_LEN * 64;
    float* hgB = hvB + (size_t)T_LEN * 32;     // h region < NE/2
    float* pk  = ws + 4 * NE + NE / 2;         // 6*NE floats (16*1024*768)
    unsigned short* b16 = (unsigned short*)(ws + 10 * NE + NE / 2);
    unsigned short* xr16 = b16;                // NE shorts
    unsigned short* xk16 = b16 + NE;
    unsigned short* xv16 = b16 + 2 * NE;
    unsigned short* Wr16 = b16 + 3 * NE;       // 4*WE shorts
    unsigned short* Wk16 = Wr16 + WE;
    unsigned short* Wv16 = Wr16 + 2 * WE;
    unsigned short* Wo16 = Wr16 + 3 * WE;
    unsigned short* yg16 = b16 + 3 * NE + 4 * WE;  // NE shorts
    unsigned short* lw16 = yg16 + NE;              // 320K shorts (LoRA weights)
    // xw/xa/xg bf16 live in the pk region (pk written later by lora2f)
    unsigned short* xw16 = (unsigned short*)pk;
    unsigned short* xa16 = xw16 + NE;
    unsigned short* xg16 = xw16 + 2 * NE;
    // yB aliases xr16/xk16 (consumed by gemms before vscan writes it)
    float* yB = (float*)xr16;

    wcvtall<<<4384, 256, 0, stream>>>(Wr, Wk, Wv, Wo, w1, a1, v1, g1,
                                      Wr16, lw16);
    xcvt<<<T_LEN, 256, 0, stream>>>(x, x_prev, x_r, x_k, x_v, x_w, x_a, x_g,
                                    xr16, xk16, xv16, xw16, xa16, xg16);

    gemm_bf16_3<<<dim3(16, 16, 3), 256, 0, stream>>>(
        xr16, xk16, xv16, Wr16, Wk16, Wv16, rB, kB, vB);

    lora1m<<<dim3(2, 16, 4), 256, 0, stream>>>(
        xw16, xa16, xv16, xg16, lw16, hwB, haB, hvB, hgB);

    lora2f<<<dim3(4, 128), 256, 0, stream>>>(
        hwB, haB, hvB, hgB, w2, a2, v2, g2, w0, a0, v0,
        k_k, k_a, v_first, rB, kB, vB, gB, pk);

    vscan<<<256, 64, 0, stream>>>(pk, init_st, yB);
    gn_bonus<<<T_LEN, 256, 0, stream>>>(yB, rB, kB, vB, gB, r_k, ln_w, ln_b, yg16);
    gemm_bf16<<<dim3(16, 16), 256, 0, stream>>>(yg16, Wo16, out);
}

// Round 3
// 521.474 us; speedup vs baseline: 1.0897x; 1.0897x over previous
//
#include <hip/hip_runtime.h>

#define T_LEN 2048
#define C_DIM 1024
#define PAIR_F 768          // floats per (head, step-pair) packet
#define BPAIR 4             // pairs per vscan LDS batch
#define BATCH_F (BPAIR * PAIR_F)   // 3072 floats, contiguous per batch

#define AS1 __attribute__((address_space(1)))
#define AS3 __attribute__((address_space(3)))
#define VM_FENCE0() asm volatile("s_waitcnt vmcnt(0)" ::: "memory")
#define C_FENCE() asm volatile("" ::: "memory")
#define VM_FENCE8() asm volatile("s_waitcnt vmcnt(8)" ::: "memory")

typedef __attribute__((ext_vector_type(8))) short bf8_t;
typedef __attribute__((ext_vector_type(4))) float f4_t;
typedef __attribute__((ext_vector_type(2))) float f2_t;

static __device__ __forceinline__ float sigf(float x) {
    return 1.f / (1.f + __expf(-x));
}
static __device__ __forceinline__ unsigned short f2bf(float f) {
    unsigned u = __float_as_uint(f);
    u += 0x7fff + ((u >> 16) & 1);
    return (unsigned short)(u >> 16);
}

// ---------------------------------------------------------------------------
// Convert the four 1024x1024 fp32 weights into one bf16 block (1M strides),
// plus the transposed LoRA stage-1 weights (blocks 4096..4383).
// lw16 layout: w1t[64][1024] | a1t[64][1024] | v1t[64][1024] | g1t[128][1024]
// ---------------------------------------------------------------------------
__global__ __launch_bounds__(256) void wcvtall(
    const float* __restrict__ Wr, const float* __restrict__ Wk,
    const float* __restrict__ Wv, const float* __restrict__ Wo,
    const float* __restrict__ w1, const float* __restrict__ a1,
    const float* __restrict__ v1, const float* __restrict__ g1,
    unsigned short* __restrict__ dst, unsigned short* __restrict__ lw16)
{
    const int b = blockIdx.x;
    if (b < 4096) {
        const size_t idx = ((size_t)b * 256 + threadIdx.x) * 4;
        const int sel = (int)(idx >> 20);
        const float* src = sel == 0 ? Wr : sel == 1 ? Wk : sel == 2 ? Wv : Wo;
        float4 v = *(const float4*)(src + (idx & 0xFFFFF));
        ushort4 o = {f2bf(v.x), f2bf(v.y), f2bf(v.z), f2bf(v.w)};
        *(ushort4*)(dst + idx) = o;
        return;
    }
    const int row = b - 4096;         // 0..287
    const float* src; int Kh, i; unsigned short* dl;
    if (row < 64)       { src = w1; Kh = 64;  i = row;       dl = lw16 + (size_t)row * 1024; }
    else if (row < 128) { src = a1; Kh = 64;  i = row - 64;  dl = lw16 + (size_t)row * 1024; }
    else if (row < 160) { src = v1; Kh = 32;  i = row - 128; dl = lw16 + (size_t)(row - 128 + 128) * 1024; }
    else                { src = g1; Kh = 128; i = row - 160; dl = lw16 + (size_t)(row - 160 + 192) * 1024; }
    const int c0 = threadIdx.x * 4;
#pragma unroll
    for (int u = 0; u < 4; ++u)
        dl[c0 + u] = f2bf(src[(size_t)(c0 + u) * Kh + i]);
}

// ---------------------------------------------------------------------------
// Token-shift mix -> bf16 A-matrices for r/k/v projections and w/a/g LoRA.
// ---------------------------------------------------------------------------
__global__ __launch_bounds__(256) void xcvt(
    const float* __restrict__ x, const float* __restrict__ xprev,
    const float* __restrict__ x_r, const float* __restrict__ x_k,
    const float* __restrict__ x_v, const float* __restrict__ x_w,
    const float* __restrict__ x_a, const float* __restrict__ x_g,
    unsigned short* __restrict__ xr16, unsigned short* __restrict__ xk16,
    unsigned short* __restrict__ xv16, unsigned short* __restrict__ xw16,
    unsigned short* __restrict__ xa16, unsigned short* __restrict__ xg16)
{
    const int t = blockIdx.x;
    const int c0 = threadIdx.x * 4;
    const size_t base = (size_t)t * C_DIM + c0;
    float4 xv = *(const float4*)(x + base);
    float4 pv = (t == 0) ? *(const float4*)(xprev + c0)
                         : *(const float4*)(x + base - C_DIM);
    float4 dx = {pv.x - xv.x, pv.y - xv.y, pv.z - xv.z, pv.w - xv.w};
#define MIXOUT(mixp, dstp)                                                    \
    {                                                                          \
        float4 mv = *(const float4*)(mixp + c0);                               \
        ushort4 o = {f2bf(xv.x + dx.x * mv.x), f2bf(xv.y + dx.y * mv.y),       \
                     f2bf(xv.z + dx.z * mv.z), f2bf(xv.w + dx.w * mv.w)};      \
        *(ushort4*)(dstp + base) = o;                                          \
    }
    MIXOUT(x_r, xr16) MIXOUT(x_k, xk16) MIXOUT(x_v, xv16)
    MIXOUT(x_w, xw16) MIXOUT(x_a, xa16) MIXOUT(x_g, xg16)
#undef MIXOUT
}

// ---------------------------------------------------------------------------
// bf16 MFMA NT GEMM core: out[t,i] = sum_c A[t,c]*W[i,c], fp32 accumulate.
// ---------------------------------------------------------------------------
static __device__ __forceinline__ void gemm_core(
    const unsigned short* __restrict__ A, const unsigned short* __restrict__ W,
    float* __restrict__ out)
{
    __shared__ unsigned short Ab[2][128 * 32];
    __shared__ unsigned short Bb[2][64 * 32];
    const int tid = threadIdx.x;
    const int lane = tid & 63;
    const int w = tid >> 6;
    const int n0 = blockIdx.x * 64;
    const int t0 = blockIdx.y * 128;
    const int wm = (w & 1) * 64;
    const int wn = (w >> 1) * 32;
    const int srow = lane >> 2;
    const int scol = (lane & 3) * 8;

    f4_t acc[4][2];
#pragma unroll
    for (int i = 0; i < 4; ++i)
#pragma unroll
        for (int j = 0; j < 2; ++j)
            acc[i][j] = (f4_t){0.f, 0.f, 0.f, 0.f};

#pragma unroll
    for (int s = 0; s < 2; ++s) {
        const int i = 2 * w + s;
        __builtin_amdgcn_global_load_lds(
            (const AS1 unsigned int*)(A + (size_t)(t0 + i * 16 + srow) * 1024 + scol),
            (AS3 unsigned int*)(&Ab[0][i * 512 + lane * 8]), 16, 0, 0);
    }
    __builtin_amdgcn_global_load_lds(
        (const AS1 unsigned int*)(W + (size_t)(n0 + w * 16 + srow) * 1024 + scol),
        (AS3 unsigned int*)(&Bb[0][w * 512 + lane * 8]), 16, 0, 0);

    const int mrow = lane & 15;
    const int kq = (lane >> 4) * 8;
    for (int k0 = 0; k0 < 1024; k0 += 32) {
        const int cur = (k0 >> 5) & 1, nxt = cur ^ 1;
        __syncthreads();
        if (k0 + 32 < 1024) {
            const int k1 = k0 + 32;
#pragma unroll
            for (int s = 0; s < 2; ++s) {
                const int i = 2 * w + s;
                __builtin_amdgcn_global_load_lds(
                    (const AS1 unsigned int*)(A + (size_t)(t0 + i * 16 + srow) * 1024 + k1 + scol),
                    (AS3 unsigned int*)(&Ab[nxt][i * 512 + lane * 8]), 16, 0, 0);
            }
            __builtin_amdgcn_global_load_lds(
                (const AS1 unsigned int*)(W + (size_t)(n0 + w * 16 + srow) * 1024 + k1 + scol),
                (AS3 unsigned int*)(&Bb[nxt][w * 512 + lane * 8]), 16, 0, 0);
        }
        bf8_t af[4], bfr[2];
#pragma unroll
        for (int i = 0; i < 4; ++i)
            af[i] = *(const bf8_t*)(&Ab[cur][(wm + 16 * i + mrow) * 32 + kq]);
#pragma unroll
        for (int j = 0; j < 2; ++j)
            bfr[j] = *(const bf8_t*)(&Bb[cur][(wn + 16 * j + mrow) * 32 + kq]);
#pragma unroll
        for (int i = 0; i < 4; ++i)
#pragma unroll
            for (int j = 0; j < 2; ++j)
                acc[i][j] = __builtin_amdgcn_mfma_f32_16x16x32_bf16(
                    af[i], bfr[j], acc[i][j], 0, 0, 0);
    }
    const int crow = (lane >> 4) * 4;
    const int ccol = lane & 15;
#pragma unroll
    for (int i = 0; i < 4; ++i)
#pragma unroll
        for (int j = 0; j < 2; ++j)
#pragma unroll
            for (int u = 0; u < 4; ++u)
                out[(size_t)(t0 + wm + 16 * i + crow + u) * 1024
                    + n0 + wn + 16 * j + ccol] = acc[i][j][u];
}

__global__ __launch_bounds__(256) void gemm_bf16_3(
    const unsigned short* __restrict__ xr, const unsigned short* __restrict__ xk,
    const unsigned short* __restrict__ xv,
    const unsigned short* __restrict__ Wr, const unsigned short* __restrict__ Wk,
    const unsigned short* __restrict__ Wv,
    float* __restrict__ rB, float* __restrict__ kB, float* __restrict__ vB)
{
    const int z = blockIdx.z;
    const unsigned short* A = z == 0 ? xr : z == 1 ? xk : xv;
    const unsigned short* W = z == 0 ? Wr : z == 1 ? Wk : Wv;
    float* out = z == 0 ? rB : z == 1 ? kB : vB;
    gemm_core(A, W, out);
}

__global__ __launch_bounds__(256) void gemm_bf16(
    const unsigned short* __restrict__ A, const unsigned short* __restrict__ W,
    float* __restrict__ out)
{
    gemm_core(A, W, out);
}

// ---------------------------------------------------------------------------
// Fused LoRA stage-1 via MFMA: z = 0:w(tanh,N=64) 1:a(N=64) 2:v(N=32) 3:g(sig,N=128)
// ---------------------------------------------------------------------------
__global__ __launch_bounds__(256) void lora1m(
    const unsigned short* __restrict__ xw, const unsigned short* __restrict__ xa,
    const unsigned short* __restrict__ xv, const unsigned short* __restrict__ xg,
    const unsigned short* __restrict__ lw16,
    float* __restrict__ hw, float* __restrict__ ha, float* __restrict__ hv,
    float* __restrict__ hg)
{
    const int z = blockIdx.z;
    const unsigned short* A = z == 0 ? xw : z == 1 ? xa : z == 2 ? xv : xg;
    const unsigned short* W = lw16 + (size_t)(z == 0 ? 0 : z == 1 ? 64 : z == 2 ? 128 : 192) * 1024;
    float* out = z == 0 ? hw : z == 1 ? ha : z == 2 ? hv : hg;
    const int N  = z == 3 ? 128 : z == 2 ? 32 : 64;
    const int Ns = z == 3 ? 128 : 64;
    const int n0 = blockIdx.x * 64;
    if (n0 >= Ns) return;

    __shared__ unsigned short Ab[2][128 * 32];
    __shared__ unsigned short Bb[2][64 * 32];
    const int tid = threadIdx.x;
    const int lane = tid & 63;
    const int w = tid >> 6;
    const int t0 = blockIdx.y * 128;
    const int wm = (w & 1) * 64;
    const int wn = (w >> 1) * 32;
    const int srow = lane >> 2;
    const int scol = (lane & 3) * 8;

    f4_t acc[4][2];
#pragma unroll
    for (int i = 0; i < 4; ++i)
#pragma unroll
        for (int j = 0; j < 2; ++j)
            acc[i][j] = (f4_t){0.f, 0.f, 0.f, 0.f};

#pragma unroll
    for (int s = 0; s < 2; ++s) {
        const int i = 2 * w + s;
        __builtin_amdgcn_global_load_lds(
            (const AS1 unsigned int*)(A + (size_t)(t0 + i * 16 + srow) * 1024 + scol),
            (AS3 unsigned int*)(&Ab[0][i * 512 + lane * 8]), 16, 0, 0);
    }
    __builtin_amdgcn_global_load_lds(
        (const AS1 unsigned int*)(W + (size_t)(n0 + w * 16 + srow) * 1024 + scol),
        (AS3 unsigned int*)(&Bb[0][w * 512 + lane * 8]), 16, 0, 0);

    const int mrow = lane & 15;
    const int kq = (lane >> 4) * 8;
    for (int k0 = 0; k0 < 1024; k0 += 32) {
        const int cur = (k0 >> 5) & 1, nxt = cur ^ 1;
        __syncthreads();
        if (k0 + 32 < 1024) {
            const int k1 = k0 + 32;
#pragma unroll
            for (int s = 0; s < 2; ++s) {
                const int i = 2 * w + s;
                __builtin_amdgcn_global_load_lds(
                    (const AS1 unsigned int*)(A + (size_t)(t0 + i * 16 + srow) * 1024 + k1 + scol),
                    (AS3 unsigned int*)(&Ab[nxt][i * 512 + lane * 8]), 16, 0, 0);
            }
            __builtin_amdgcn_global_load_lds(
                (const AS1 unsigned int*)(W + (size_t)(n0 + w * 16 + srow) * 1024 + k1 + scol),
                (AS3 unsigned int*)(&Bb[nxt][w * 512 + lane * 8]), 16, 0, 0);
        }
        bf8_t af[4], bfr[2];
#pragma unroll
        for (int i = 0; i < 4; ++i)
            af[i] = *(const bf8_t*)(&Ab[cur][(wm + 16 * i + mrow) * 32 + kq]);
#pragma unroll
        for (int j = 0; j < 2; ++j)
            bfr[j] = *(const bf8_t*)(&Bb[cur][(wn + 16 * j + mrow) * 32 + kq]);
#pragma unroll
        for (int i = 0; i < 4; ++i)
#pragma unroll
            for (int j = 0; j < 2; ++j)
                acc[i][j] = __builtin_amdgcn_mfma_f32_16x16x32_bf16(
                    af[i], bfr[j], acc[i][j], 0, 0, 0);
    }
    const int crow = (lane >> 4) * 4;
    const int ccol = lane & 15;
#pragma unroll
    for (int i = 0; i < 4; ++i)
#pragma unroll
        for (int j = 0; j < 2; ++j) {
            const int col = n0 + wn + 16 * j + ccol;
            if (col < N) {
#pragma unroll
                for (int u = 0; u < 4; ++u) {
                    float vv = acc[i][j][u];
                    if (z == 0) vv = tanhf(vv);
                    else if (z == 3) vv = sigf(vv);
                    out[(size_t)(t0 + wm + 16 * i + crow + u) * N + col] = vv;
                }
            }
        }
}

// ---------------------------------------------------------------------------
// Fused LoRA-2 (w/a/v/g) + k post-process + PAIR-COMPOSED packet packing.
// Block = 16 tokens x 256 channels; head = 64 consecutive channels = 1 wave.
// Per step-pair packet (768 floats):
//   E=e1e2 @0 | A1=aa1 @64 | A2e=e1*aa2 @128 | B1e=bb1*e2 @192 | K1e=k1*e2 @256
//   | B2=bb2 @320 | K2=k2 @384 | R1e=e1*r1 @448 | R2=r2 @512 | V1 @576 | V2 @640
//   | scalars @704: cba=bb1.aa2, cka=k1.aa2, cbr=bb1.r1, ckr=k1.r1
//   | scalars @708: cbr2=B1e.r2, ckr2=K1e.r2, cb2r2=bb2.r2, ck2r2=k2.r2
//     (enables o2 = S_old.(E*R2) + sa1*cbr2 + v1*ckr2 + sa2*cb2r2 + v2*ck2r2
//      so ALL FOUR vscan reductions run in parallel from S_old)
// ---------------------------------------------------------------------------
__global__ __launch_bounds__(256) void lora2f(
    const float* __restrict__ hwB, const float* __restrict__ haB,
    const float* __restrict__ hvB, const float* __restrict__ hgB,
    const float* __restrict__ w2, const float* __restrict__ a2,
    const float* __restrict__ v2, const float* __restrict__ g2,
    const float* __restrict__ w0, const float* __restrict__ a0,
    const float* __restrict__ v0,
    const float* __restrict__ k_k, const float* __restrict__ k_a,
    const float* __restrict__ v_first, const float* __restrict__ rB,
    float* __restrict__ kB, float* __restrict__ vB, float* __restrict__ gB,
    float* __restrict__ pk)
{
    __shared__ __align__(16) float hsW[16 * 64], hsA[16 * 64];
    __shared__ __align__(16) float hsV[16 * 32], hsG[16 * 128];
    const int tid = threadIdx.x;
    const int t0 = blockIdx.y * 16;
    const int i  = blockIdx.x * 256 + tid;
    const int h  = i >> 6;
    const int j  = i & 63;
    for (int idx = tid; idx < 16 * 64; idx += 256) {
        hsW[idx] = hwB[(size_t)t0 * 64 + idx];
        hsA[idx] = haB[(size_t)t0 * 64 + idx];
    }
    for (int idx = tid; idx < 16 * 32; idx += 256)
        hsV[idx] = hvB[(size_t)t0 * 32 + idx];
    for (int idx = tid; idx < 16 * 128; idx += 256)
        hsG[idx] = hgB[(size_t)t0 * 128 + idx];
    __syncthreads();

    float av[16], ew[16], vf[16];
    { // a = sigmoid(a0 + ha@a2)
        float acc[16];
        const float b0 = a0[i];
#pragma unroll
        for (int tt = 0; tt < 16; ++tt) acc[tt] = b0;
        for (int jj = 0; jj < 64; jj += 4) {
            const float q0 = a2[(size_t)(jj + 0) * C_DIM + i];
            const float q1 = a2[(size_t)(jj + 1) * C_DIM + i];
            const float q2 = a2[(size_t)(jj + 2) * C_DIM + i];
            const float q3 = a2[(size_t)(jj + 3) * C_DIM + i];
#pragma unroll
            for (int tt = 0; tt < 16; ++tt) {
                float4 h4 = *(const float4*)(hsA + tt * 64 + jj);
                acc[tt] = fmaf(h4.x, q0, acc[tt]);
                acc[tt] = fmaf(h4.y, q1, acc[tt]);
                acc[tt] = fmaf(h4.z, q2, acc[tt]);
                acc[tt] = fmaf(h4.w, q3, acc[tt]);
            }
        }
#pragma unroll
        for (int tt = 0; tt < 16; ++tt) av[tt] = sigf(acc[tt]);
    }
    { // exp(w)
        float acc[16];
        const float b0 = w0[i];
#pragma unroll
        for (int tt = 0; tt < 16; ++tt) acc[tt] = b0;
        for (int jj = 0; jj < 64; jj += 4) {
            const float q0 = w2[(size_t)(jj + 0) * C_DIM + i];
            const float q1 = w2[(size_t)(jj + 1) * C_DIM + i];
            const float q2 = w2[(size_t)(jj + 2) * C_DIM + i];
            const float q3 = w2[(size_t)(jj + 3) * C_DIM + i];
#pragma unroll
            for (int tt = 0; tt < 16; ++tt) {
                float4 h4 = *(const float4*)(hsW + tt * 64 + jj);
                acc[tt] = fmaf(h4.x, q0, acc[tt]);
                acc[tt] = fmaf(h4.y, q1, acc[tt]);
                acc[tt] = fmaf(h4.z, q2, acc[tt]);
                acc[tt] = fmaf(h4.w, q3, acc[tt]);
            }
        }
#pragma unroll
        for (int tt = 0; tt < 16; ++tt)
            ew[tt] = __expf(-0.6065306597126334f * sigf(acc[tt]));
    }
    { // v mix
        float acc[16];
        const float b0 = v0[i];
#pragma unroll
        for (int tt = 0; tt < 16; ++tt) acc[tt] = b0;
        for (int jj = 0; jj < 32; jj += 4) {
            const float q0 = v2[(size_t)(jj + 0) * C_DIM + i];
            const float q1 = v2[(size_t)(jj + 1) * C_DIM + i];
            const float q2 = v2[(size_t)(jj + 2) * C_DIM + i];
            const float q3 = v2[(size_t)(jj + 3) * C_DIM + i];
#pragma unroll
            for (int tt = 0; tt < 16; ++tt) {
                float4 h4 = *(const float4*)(hsV + tt * 32 + jj);
                acc[tt] = fmaf(h4.x, q0, acc[tt]);
                acc[tt] = fmaf(h4.y, q1, acc[tt]);
                acc[tt] = fmaf(h4.z, q2, acc[tt]);
                acc[tt] = fmaf(h4.w, q3, acc[tt]);
            }
        }
#pragma unroll
        for (int tt = 0; tt < 16; ++tt) {
            const size_t gi = (size_t)(t0 + tt) * C_DIM + i;
            const float s = sigf(acc[tt]);
            const float vr = vB[gi];
            vf[tt] = vr + (v_first[gi] - vr) * s;
            vB[gi] = vf[tt];
        }
    }
    { // g
        float acc[16];
#pragma unroll
        for (int tt = 0; tt < 16; ++tt) acc[tt] = 0.f;
        for (int jj = 0; jj < 128; jj += 4) {
            const float q0 = g2[(size_t)(jj + 0) * C_DIM + i];
            const float q1 = g2[(size_t)(jj + 1) * C_DIM + i];
            const float q2 = g2[(size_t)(jj + 2) * C_DIM + i];
            const float q3 = g2[(size_t)(jj + 3) * C_DIM + i];
#pragma unroll
            for (int tt = 0; tt < 16; ++tt) {
                float4 h4 = *(const float4*)(hsG + tt * 128 + jj);
                acc[tt] = fmaf(h4.x, q0, acc[tt]);
                acc[tt] = fmaf(h4.y, q1, acc[tt]);
                acc[tt] = fmaf(h4.z, q2, acc[tt]);
                acc[tt] = fmaf(h4.w, q3, acc[tt]);
            }
        }
#pragma unroll
        for (int tt = 0; tt < 16; ++tt)
            gB[(size_t)(t0 + tt) * C_DIM + i] = acc[tt];
    }
    // k post-process + pair-composed packing
    const float kkw = k_k[i], kaw = k_a[i];
    const size_t pbase = (size_t)h * 1024 * PAIR_F;
    for (int pt = 0; pt < 8; ++pt) {
        float r_[2], e_[2], kf_[2], v_[2], aa_[2], bb_[2];
#pragma unroll
        for (int u = 0; u < 2; ++u) {
            const int tt = 2 * pt + u;
            const size_t gi = (size_t)(t0 + tt) * C_DIM + i;
            const float kraw = kB[gi];
            const float kn = kraw * kkw;
            float ss = kn * kn;
#pragma unroll
            for (int m = 1; m <= 32; m <<= 1) ss += __shfl_xor(ss, m);
            const float sc = 1.f / fmaxf(sqrtf(ss), 1e-12f);
            const float kk = kn * sc;
            const float a_ = av[tt];
            const float kf = kraw * (1.f + (a_ - 1.f) * kaw);
            kB[gi] = kf;
            r_[u] = rB[gi];
            e_[u] = ew[tt];
            kf_[u] = kf;
            v_[u] = vf[tt];
            aa_[u] = -kk;
            bb_[u] = kk * a_;
        }
        const float E   = e_[0] * e_[1];
        const float A2e = e_[0] * aa_[1];
        const float B1e = bb_[0] * e_[1];
        const float K1e = kf_[0] * e_[1];
        const float R1e = e_[0] * r_[0];
        float cba = bb_[0] * aa_[1];
        float cka = kf_[0] * aa_[1];
        float cbr = bb_[0] * r_[0];
        float ckr = kf_[0] * r_[0];
        // o2-decomposition cross-scalars (dots against R2 = r_[1])
        float cbr2  = B1e * r_[1];
        float ckr2  = K1e * r_[1];
        float cb2r2 = bb_[1] * r_[1];
        float ck2r2 = kf_[1] * r_[1];
#pragma unroll
        for (int m = 1; m <= 32; m <<= 1) {
            cba += __shfl_xor(cba, m);
            cka += __shfl_xor(cka, m);
            cbr += __shfl_xor(cbr, m);
            ckr += __shfl_xor(ckr, m);
            cbr2  += __shfl_xor(cbr2, m);
            ckr2  += __shfl_xor(ckr2, m);
            cb2r2 += __shfl_xor(cb2r2, m);
            ck2r2 += __shfl_xor(ck2r2, m);
        }
        float* p = pk + pbase + (size_t)(blockIdx.y * 8 + pt) * PAIR_F;
        p[j]        = E;
        p[64 + j]   = aa_[0];
        p[128 + j]  = A2e;
        p[192 + j]  = B1e;
        p[256 + j]  = K1e;
        p[320 + j]  = bb_[1];
        p[384 + j]  = kf_[1];
        p[448 + j]  = R1e;
        p[512 + j]  = r_[1];
        p[576 + j]  = v_[0];
        p[640 + j]  = v_[1];
        if (j == 0) {
            p[704] = cba;  p[705] = cka;  p[706] = cbr;  p[707] = ckr;
            p[708] = cbr2; p[709] = ckr2; p[710] = cb2r2; p[711] = ck2r2;
        }
    }
}

// ---------------------------------------------------------------------------
// v-row-parallel scan over step-PAIRS. 256 blocks x 64 threads; block b ->
// head (b&15). Per pair: FOUR independent 16-lane reductions (u1,u2,o1,oz)
// all launched from S_old (o2 decomposed via @708 cross-scalars), scalar
// fixups, packed-FP32 5-term update. Double-buffered LDS (r1 best config).
// sched_barrier(0) pins pair_read(s+1) before pair_compute(s).
// ---------------------------------------------------------------------------
struct Pair {
    float4 E, A1, A2e, B1e, K1e, B2, K2, R1e, R2;
    float v1, v2;
    float4 sc;    // cba, cka, cbr, ckr
    float4 sc2;   // cbr2, ckr2, cb2r2, ck2r2
};

static __device__ __forceinline__ float red16(float x) {
    int xi;
    xi = __builtin_amdgcn_mov_dpp(__float_as_int(x), 0x128, 0xf, 0xf, true);
    x += __int_as_float(xi);
    xi = __builtin_amdgcn_mov_dpp(__float_as_int(x), 0x124, 0xf, 0xf, true);
    x += __int_as_float(xi);
    xi = __builtin_amdgcn_mov_dpp(__float_as_int(x), 0x122, 0xf, 0xf, true);
    x += __int_as_float(xi);
    xi = __builtin_amdgcn_mov_dpp(__float_as_int(x), 0x121, 0xf, 0xf, true);
    x += __int_as_float(xi);
    return x;
}

static __device__ __forceinline__ f2_t f2bc(float s) { return (f2_t){s, s}; }
static __device__ __forceinline__ f2_t fma2(f2_t a, f2_t b, f2_t c) {
    return __builtin_elementwise_fma(a, b, c);
}
static __device__ __forceinline__ f2_t lo2(const float4& v) { return (f2_t){v.x, v.y}; }
static __device__ __forceinline__ f2_t hi2(const float4& v) { return (f2_t){v.z, v.w}; }

static __device__ __forceinline__ float dot4pk(f2_t Sl, f2_t Sh, const float4& A) {
    f2_t m = Sl * lo2(A);
    m = fma2(Sh, hi2(A), m);
    return m.x + m.y;
}

static __device__ __forceinline__ void issue_batch(
    const float* __restrict__ hbase, float* __restrict__ buf, int batch, int l)
{
    const float* src = hbase + (size_t)batch * BATCH_F;
#pragma unroll
    for (int i = 0; i < BATCH_F / 256; ++i)   // 12 full-wave 16B loads
        __builtin_amdgcn_global_load_lds(
            (const AS1 unsigned int*)(src + i * 256 + l * 4),
            (AS3 unsigned int*)(&buf[i * 256 + l * 4]), 16, 0, 0);
}

static __device__ __forceinline__ Pair pair_read(
    const float* __restrict__ buf, int s, int j0, int vidx)
{
    Pair P;
    const float* p = buf + s * PAIR_F;
    P.E   = *(const float4*)(p + j0);
    P.A1  = *(const float4*)(p + 64 + j0);
    P.A2e = *(const float4*)(p + 128 + j0);
    P.B1e = *(const float4*)(p + 192 + j0);
    P.K1e = *(const float4*)(p + 256 + j0);
    P.B2  = *(const float4*)(p + 320 + j0);
    P.K2  = *(const float4*)(p + 384 + j0);
    P.R1e = *(const float4*)(p + 448 + j0);
    P.R2  = *(const float4*)(p + 512 + j0);
    P.v1  = p[576 + vidx];
    P.v2  = p[640 + vidx];
    P.sc  = *(const float4*)(p + 704);
    P.sc2 = *(const float4*)(p + 708);
    return P;
}

static __device__ __forceinline__ void pair_compute(
    f2_t& Sl, f2_t& Sh, const Pair& P, float* __restrict__ y,
    int pi, int cb, int vidx, int lane)
{
    // E ⊙ R2 for the parallel o2 partial
    const f2_t er2l = lo2(P.E) * lo2(P.R2);
    const f2_t er2h = hi2(P.E) * hi2(P.R2);
    // FOUR independent reductions, all from S_old — chains interleave,
    // no solo DPP chain remains on the critical path.
    const float u1 = red16(dot4pk(Sl, Sh, P.A1));
    const float u2 = red16(dot4pk(Sl, Sh, P.A2e));
    float o1       = red16(dot4pk(Sl, Sh, P.R1e));
    f2_t mz = Sl * er2l; mz = fma2(Sh, er2h, mz);
    const float oz = red16(mz.x + mz.y);

    const float sa1 = u1;
    const float sa2 = fmaf(P.v1, P.sc.y, fmaf(sa1, P.sc.x, u2));
    o1 = fmaf(P.v1, P.sc.w, fmaf(sa1, P.sc.z, o1));
    const float o2 = fmaf(P.v2, P.sc2.w, fmaf(sa2, P.sc2.z,
                     fmaf(P.v1, P.sc2.y, fmaf(sa1, P.sc2.x, oz))));
    if ((lane & 15) == 0) {
        y[(size_t)(2 * pi) * C_DIM + cb + vidx] = o1;
        y[(size_t)(2 * pi + 1) * C_DIM + cb + vidx] = o2;
    }
    // S = S*E + sa1*B1e + v1*K1e + sa2*B2 + v2*K2  (packed FP32, 2 halves)
    const f2_t sa1v = f2bc(sa1), sa2v = f2bc(sa2);
    const f2_t v1v = f2bc(P.v1), v2v = f2bc(P.v2);
    f2_t nl = Sl * lo2(P.E);
    f2_t nh = Sh * hi2(P.E);
    nl = fma2(sa1v, lo2(P.B1e), nl);
    nh = fma2(sa1v, hi2(P.B1e), nh);
    nl = fma2(v1v, lo2(P.K1e), nl);
    nh = fma2(v1v, hi2(P.K1e), nh);
    nl = fma2(sa2v, lo2(P.B2), nl);
    nh = fma2(sa2v, hi2(P.B2), nh);
    nl = fma2(v2v, lo2(P.K2), nl);
    nh = fma2(v2v, hi2(P.K2), nh);
    Sl = nl; Sh = nh;
}

__global__ __launch_bounds__(64) void vscan(
    const float* __restrict__ pk, const float* __restrict__ init_state,
    float* __restrict__ y)
{
    const int h  = blockIdx.x & 15;     // b%8 == h%8 -> per-head XCD locality
    const int wv = blockIdx.x >> 4;
    const int l  = threadIdx.x;
    const int vidx = wv * 4 + (l >> 4);
    const int j0 = (l & 15) * 4;
    const int cb = h * 64;

    __shared__ __align__(16) float buf[2][BATCH_F];
    const float* hbase = pk + (size_t)h * 1024 * PAIR_F;

    float4 S4 = *(const float4*)(init_state + h * 4096 + vidx * 64 + j0);
    f2_t Sl = {S4.x, S4.y};
    f2_t Sh = {S4.z, S4.w};

    issue_batch(hbase, buf[0], 0, l);
    VM_FENCE0();
    Pair cur = pair_read(buf[0], 0, j0, vidx);
    const int NB = 1024 / BPAIR;        // 256 batches
    for (int b = 0; b < NB; ++b) {
        if (b + 1 < NB)
            issue_batch(hbase, buf[(b + 1) & 1], b + 1, l);
        C_FENCE();                      // keep the 12 loads ahead of stores
        const float* cbuf = buf[b & 1];
#pragma unroll
        for (int s = 0; s < BPAIR; ++s) {
            Pair nxt;
            if (s + 1 < BPAIR) nxt = pair_read(cbuf, s + 1, j0, vidx);
            // Pin the pipeline: nxt's ds_reads issue here and may NOT sink
            // into/past the compute of cur (r1: killed all bank conflicts).
            __builtin_amdgcn_sched_barrier(0);
            pair_compute(Sl, Sh, cur, y, b * BPAIR + s, cb, vidx, l);
            if (s + 1 < BPAIR) cur = nxt;
        }
        VM_FENCE8();                    // 12 prefetch loads landed
        cur = pair_read(buf[(b + 1) & 1], 0, j0, vidx);  // junk at b=NB-1, unused
        __builtin_amdgcn_sched_barrier(0);
    }
}

// ---------------------------------------------------------------------------
// GroupNorm + bonus + *g ; writes bf16 (xo*g) for the final MFMA GEMM.
// ---------------------------------------------------------------------------
__global__ __launch_bounds__(256) void gn_bonus(
    const float* __restrict__ y, const float* __restrict__ rb,
    const float* __restrict__ kb, const float* __restrict__ vb,
    const float* __restrict__ gb, const float* __restrict__ r_k,
    const float* __restrict__ lnw, const float* __restrict__ lnb,
    unsigned short* __restrict__ yg)
{
    const int t = blockIdx.x, tid = threadIdx.x;
    const int c0 = tid << 2;
    const size_t base = (size_t)t * C_DIM + c0;
    float4 yv = *(const float4*)(y + base);
    float sum = yv.x + yv.y + yv.z + yv.w;
    float ss  = yv.x * yv.x + yv.y * yv.y + yv.z * yv.z + yv.w * yv.w;
    float4 rv = *(const float4*)(rb + base);
    float4 kv = *(const float4*)(kb + base);
    float4 rkv = *(const float4*)(r_k + c0);
    float dot = rv.x * kv.x * rkv.x + rv.y * kv.y * rkv.y +
                rv.z * kv.z * rkv.z + rv.w * kv.w * rkv.w;
#pragma unroll
    for (int m = 1; m <= 8; m <<= 1) {
        sum += __shfl_xor(sum, m);
        ss  += __shfl_xor(ss, m);
        dot += __shfl_xor(dot, m);
    }
    const float mu = sum * 0.015625f;
    const float var = ss * 0.015625f - mu * mu;
    const float rstd = rsqrtf(var + 0.00064f);
    float4 wv = *(const float4*)(lnw + c0);
    float4 bv = *(const float4*)(lnb + c0);
    float4 vv = *(const float4*)(vb + base);
    float4 gv = *(const float4*)(gb + base);
    ushort4 o;
    o.x = f2bf(((yv.x - mu) * rstd * wv.x + bv.x + dot * vv.x) * gv.x);
    o.y = f2bf(((yv.y - mu) * rstd * wv.y + bv.y + dot * vv.y) * gv.y);
    o.z = f2bf(((yv.z - mu) * rstd * wv.z + bv.z + dot * vv.z) * gv.z);
    o.w = f2bf(((yv.w - mu) * rstd * wv.w + bv.w + dot * vv.w) * gv.w);
    *(ushort4*)(yg + base) = o;
}

// ---------------------------------------------------------------------------
extern "C" void kernel_launch(void* const* d_in, const int* in_sizes, int n_in,
                              void* d_out, int out_size, void* d_ws, size_t ws_size,
                              hipStream_t stream)
{
    (void)in_sizes; (void)n_in; (void)out_size; (void)ws_size;
    const float* x       = (const float*)d_in[0];
    const float* v_first = (const float*)d_in[1];
    const float* x_prev  = (const float*)d_in[2];
    const float* init_st = (const float*)d_in[3];
    const float* x_r = (const float*)d_in[4];
    const float* x_w = (const float*)d_in[5];
    const float* x_k = (const float*)d_in[6];
    const float* x_v = (const float*)d_in[7];
    const float* x_a = (const float*)d_in[8];
    const float* x_g = (const float*)d_in[9];
    const float* w0  = (const float*)d_in[10];
    const float* a0  = (const float*)d_in[11];
    const float* v0  = (const float*)d_in[12];
    const float* k_k = (const float*)d_in[13];
    const float* k_a = (const float*)d_in[14];
    const float* w1  = (const float*)d_in[15];
    const float* w2  = (const float*)d_in[16];
    const float* a1  = (const float*)d_in[17];
    const float* a2  = (const float*)d_in[18];
    const float* v1  = (const float*)d_in[19];
    const float* v2  = (const float*)d_in[20];
    const float* g1  = (const float*)d_in[21];
    const float* g2  = (const float*)d_in[22];
    const float* r_k = (const float*)d_in[23];
    const float* Wr  = (const float*)d_in[24];
    const float* Wk  = (const float*)d_in[25];
    const float* Wv  = (const float*)d_in[26];
    const float* Wo  = (const float*)d_in[27];
    const float* ln_w = (const float*)d_in[28];
    const float* ln_b = (const float*)d_in[29];

    float* out = (float*)d_out;
    float* ws  = (float*)d_ws;
    const size_t NE = (size_t)T_LEN * C_DIM;   // 2M
    const size_t WE = (size_t)C_DIM * C_DIM;   // 1M
    float* rB  = ws;
    float* kB  = ws + NE;
    float* vB  = ws + 2 * NE;
    float* gB  = ws + 3 * NE;
    float* hwB = ws + 4 * NE;                  // T*64
    float* haB = hwB + (size_t)T_LEN * 64;
    float* hvB = haB + (size_t)T_LEN * 64;
    float* hgB = hvB + (size_t)T_LEN * 32;     // h region < NE/2
    float* pk  = ws + 4 * NE + NE / 2;         // 6*NE floats (16*1024*768)
    unsigned short* b16 = (unsigned short*)(ws + 10 * NE + NE / 2);
    unsigned short* xr16 = b16;                // NE shorts
    unsigned short* xk16 = b16 + NE;
    unsigned short* xv16 = b16 + 2 * NE;
    unsigned short* Wr16 = b16 + 3 * NE;       // 4*WE shorts
    unsigned short* Wk16 = Wr16 + WE;
    unsigned short* Wv16 = Wr16 + 2 * WE;
    unsigned short* Wo16 = Wr16 + 3 * WE;
    unsigned short* yg16 = b16 + 3 * NE + 4 * WE;  // NE shorts
    unsigned short* lw16 = yg16 + NE;              // 320K shorts (LoRA weights)
    // xw/xa/xg bf16 live in the pk region (pk written later by lora2f)
    unsigned short* xw16 = (unsigned short*)pk;
    unsigned short* xa16 = xw16 + NE;
    unsigned short* xg16 = xw16 + 2 * NE;
    // yB aliases xr16/xk16 (consumed by gemms before vscan writes it)
    float* yB = (float*)xr16;

    wcvtall<<<4384, 256, 0, stream>>>(Wr, Wk, Wv, Wo, w1, a1, v1, g1,
                                      Wr16, lw16);
    xcvt<<<T_LEN, 256, 0, stream>>>(x, x_prev, x_r, x_k, x_v, x_w, x_a, x_g,
                                    xr16, xk16, xv16, xw16, xa16, xg16);

    gemm_bf16_3<<<dim3(16, 16, 3), 256, 0, stream>>>(
        xr16, xk16, xv16, Wr16, Wk16, Wv16, rB, kB, vB);

    lora1m<<<dim3(2, 16, 4), 256, 0, stream>>>(
        xw16, xa16, xv16, xg16, lw16, hwB, haB, hvB, hgB);

    lora2f<<<dim3(4, 128), 256, 0, stream>>>(
        hwB, haB, hvB, hgB, w2, a2, v2, g2, w0, a0, v0,
        k_k, k_a, v_first, rB, kB, vB, gB, pk);

    vscan<<<256, 64, 0, stream>>>(pk, init_st, yB);
    gn_bonus<<<T_LEN, 256, 0, stream>>>(yB, rB, kB, vB, gB, r_k, ln_w, ln_b, yg16);
    gemm_bf16<<<dim3(16, 16), 256, 0, stream>>>(yg16, Wo16, out);
}

// Round 4
// 502.943 us; speedup vs baseline: 1.1299x; 1.0368x over previous
//
#include <hip/hip_runtime.h>

#define T_LEN 2048
#define C_DIM 1024
#define PAIR_F 768          // floats per (head, step-pair) packet

#define AS1 __attribute__((address_space(1)))
#define AS3 __attribute__((address_space(3)))

typedef __attribute__((ext_vector_type(8))) short bf8_t;
typedef __attribute__((ext_vector_type(4))) float f4_t;
typedef __attribute__((ext_vector_type(2))) float f2_t;

static __device__ __forceinline__ float sigf(float x) {
    return 1.f / (1.f + __expf(-x));
}
static __device__ __forceinline__ unsigned short f2bf(float f) {
    unsigned u = __float_as_uint(f);
    u += 0x7fff + ((u >> 16) & 1);
    return (unsigned short)(u >> 16);
}

// ---------------------------------------------------------------------------
// Convert the four 1024x1024 fp32 weights into one bf16 block (1M strides),
// plus the transposed LoRA stage-1 weights (blocks 4096..4383).
// lw16 layout: w1t[64][1024] | a1t[64][1024] | v1t[64][1024] | g1t[128][1024]
// ---------------------------------------------------------------------------
__global__ __launch_bounds__(256) void wcvtall(
    const float* __restrict__ Wr, const float* __restrict__ Wk,
    const float* __restrict__ Wv, const float* __restrict__ Wo,
    const float* __restrict__ w1, const float* __restrict__ a1,
    const float* __restrict__ v1, const float* __restrict__ g1,
    unsigned short* __restrict__ dst, unsigned short* __restrict__ lw16)
{
    const int b = blockIdx.x;
    if (b < 4096) {
        const size_t idx = ((size_t)b * 256 + threadIdx.x) * 4;
        const int sel = (int)(idx >> 20);
        const float* src = sel == 0 ? Wr : sel == 1 ? Wk : sel == 2 ? Wv : Wo;
        float4 v = *(const float4*)(src + (idx & 0xFFFFF));
        ushort4 o = {f2bf(v.x), f2bf(v.y), f2bf(v.z), f2bf(v.w)};
        *(ushort4*)(dst + idx) = o;
        return;
    }
    const int row = b - 4096;         // 0..287
    const float* src; int Kh, i; unsigned short* dl;
    if (row < 64)       { src = w1; Kh = 64;  i = row;       dl = lw16 + (size_t)row * 1024; }
    else if (row < 128) { src = a1; Kh = 64;  i = row - 64;  dl = lw16 + (size_t)row * 1024; }
    else if (row < 160) { src = v1; Kh = 32;  i = row - 128; dl = lw16 + (size_t)(row - 128 + 128) * 1024; }
    else                { src = g1; Kh = 128; i = row - 160; dl = lw16 + (size_t)(row - 160 + 192) * 1024; }
    const int c0 = threadIdx.x * 4;
#pragma unroll
    for (int u = 0; u < 4; ++u)
        dl[c0 + u] = f2bf(src[(size_t)(c0 + u) * Kh + i]);
}

// ---------------------------------------------------------------------------
// Token-shift mix -> bf16 A-matrices for r/k/v projections and w/a/g LoRA.
// ---------------------------------------------------------------------------
__global__ __launch_bounds__(256) void xcvt(
    const float* __restrict__ x, const float* __restrict__ xprev,
    const float* __restrict__ x_r, const float* __restrict__ x_k,
    const float* __restrict__ x_v, const float* __restrict__ x_w,
    const float* __restrict__ x_a, const float* __restrict__ x_g,
    unsigned short* __restrict__ xr16, unsigned short* __restrict__ xk16,
    unsigned short* __restrict__ xv16, unsigned short* __restrict__ xw16,
    unsigned short* __restrict__ xa16, unsigned short* __restrict__ xg16)
{
    const int t = blockIdx.x;
    const int c0 = threadIdx.x * 4;
    const size_t base = (size_t)t * C_DIM + c0;
    float4 xv = *(const float4*)(x + base);
    float4 pv = (t == 0) ? *(const float4*)(xprev + c0)
                         : *(const float4*)(x + base - C_DIM);
    float4 dx = {pv.x - xv.x, pv.y - xv.y, pv.z - xv.z, pv.w - xv.w};
#define MIXOUT(mixp, dstp)                                                    \
    {                                                                          \
        float4 mv = *(const float4*)(mixp + c0);                               \
        ushort4 o = {f2bf(xv.x + dx.x * mv.x), f2bf(xv.y + dx.y * mv.y),       \
                     f2bf(xv.z + dx.z * mv.z), f2bf(xv.w + dx.w * mv.w)};      \
        *(ushort4*)(dstp + base) = o;                                          \
    }
    MIXOUT(x_r, xr16) MIXOUT(x_k, xk16) MIXOUT(x_v, xv16)
    MIXOUT(x_w, xw16) MIXOUT(x_a, xa16) MIXOUT(x_g, xg16)
#undef MIXOUT
}

// ---------------------------------------------------------------------------
// bf16 MFMA NT GEMM core: out[t,i] = sum_c A[t,c]*W[i,c], fp32 accumulate.
// ---------------------------------------------------------------------------
static __device__ __forceinline__ void gemm_core(
    const unsigned short* __restrict__ A, const unsigned short* __restrict__ W,
    float* __restrict__ out)
{
    __shared__ unsigned short Ab[2][128 * 32];
    __shared__ unsigned short Bb[2][64 * 32];
    const int tid = threadIdx.x;
    const int lane = tid & 63;
    const int w = tid >> 6;
    const int n0 = blockIdx.x * 64;
    const int t0 = blockIdx.y * 128;
    const int wm = (w & 1) * 64;
    const int wn = (w >> 1) * 32;
    const int srow = lane >> 2;
    const int scol = (lane & 3) * 8;

    f4_t acc[4][2];
#pragma unroll
    for (int i = 0; i < 4; ++i)
#pragma unroll
        for (int j = 0; j < 2; ++j)
            acc[i][j] = (f4_t){0.f, 0.f, 0.f, 0.f};

#pragma unroll
    for (int s = 0; s < 2; ++s) {
        const int i = 2 * w + s;
        __builtin_amdgcn_global_load_lds(
            (const AS1 unsigned int*)(A + (size_t)(t0 + i * 16 + srow) * 1024 + scol),
            (AS3 unsigned int*)(&Ab[0][i * 512 + lane * 8]), 16, 0, 0);
    }
    __builtin_amdgcn_global_load_lds(
        (const AS1 unsigned int*)(W + (size_t)(n0 + w * 16 + srow) * 1024 + scol),
        (AS3 unsigned int*)(&Bb[0][w * 512 + lane * 8]), 16, 0, 0);

    const int mrow = lane & 15;
    const int kq = (lane >> 4) * 8;
    for (int k0 = 0; k0 < 1024; k0 += 32) {
        const int cur = (k0 >> 5) & 1, nxt = cur ^ 1;
        __syncthreads();
        if (k0 + 32 < 1024) {
            const int k1 = k0 + 32;
#pragma unroll
            for (int s = 0; s < 2; ++s) {
                const int i = 2 * w + s;
                __builtin_amdgcn_global_load_lds(
                    (const AS1 unsigned int*)(A + (size_t)(t0 + i * 16 + srow) * 1024 + k1 + scol),
                    (AS3 unsigned int*)(&Ab[nxt][i * 512 + lane * 8]), 16, 0, 0);
            }
            __builtin_amdgcn_global_load_lds(
                (const AS1 unsigned int*)(W + (size_t)(n0 + w * 16 + srow) * 1024 + k1 + scol),
                (AS3 unsigned int*)(&Bb[nxt][w * 512 + lane * 8]), 16, 0, 0);
        }
        bf8_t af[4], bfr[2];
#pragma unroll
        for (int i = 0; i < 4; ++i)
            af[i] = *(const bf8_t*)(&Ab[cur][(wm + 16 * i + mrow) * 32 + kq]);
#pragma unroll
        for (int j = 0; j < 2; ++j)
            bfr[j] = *(const bf8_t*)(&Bb[cur][(wn + 16 * j + mrow) * 32 + kq]);
#pragma unroll
        for (int i = 0; i < 4; ++i)
#pragma unroll
            for (int j = 0; j < 2; ++j)
                acc[i][j] = __builtin_amdgcn_mfma_f32_16x16x32_bf16(
                    af[i], bfr[j], acc[i][j], 0, 0, 0);
    }
    const int crow = (lane >> 4) * 4;
    const int ccol = lane & 15;
#pragma unroll
    for (int i = 0; i < 4; ++i)
#pragma unroll
        for (int j = 0; j < 2; ++j)
#pragma unroll
            for (int u = 0; u < 4; ++u)
                out[(size_t)(t0 + wm + 16 * i + crow + u) * 1024
                    + n0 + wn + 16 * j + ccol] = acc[i][j][u];
}

__global__ __launch_bounds__(256) void gemm_bf16_3(
    const unsigned short* __restrict__ xr, const unsigned short* __restrict__ xk,
    const unsigned short* __restrict__ xv,
    const unsigned short* __restrict__ Wr, const unsigned short* __restrict__ Wk,
    const unsigned short* __restrict__ Wv,
    float* __restrict__ rB, float* __restrict__ kB, float* __restrict__ vB)
{
    const int z = blockIdx.z;
    const unsigned short* A = z == 0 ? xr : z == 1 ? xk : xv;
    const unsigned short* W = z == 0 ? Wr : z == 1 ? Wk : Wv;
    float* out = z == 0 ? rB : z == 1 ? kB : vB;
    gemm_core(A, W, out);
}

__global__ __launch_bounds__(256) void gemm_bf16(
    const unsigned short* __restrict__ A, const unsigned short* __restrict__ W,
    float* __restrict__ out)
{
    gemm_core(A, W, out);
}

// ---------------------------------------------------------------------------
// Fused LoRA stage-1 via MFMA: z = 0:w(tanh,N=64) 1:a(N=64) 2:v(N=32) 3:g(sig,N=128)
// ---------------------------------------------------------------------------
__global__ __launch_bounds__(256) void lora1m(
    const unsigned short* __restrict__ xw, const unsigned short* __restrict__ xa,
    const unsigned short* __restrict__ xv, const unsigned short* __restrict__ xg,
    const unsigned short* __restrict__ lw16,
    float* __restrict__ hw, float* __restrict__ ha, float* __restrict__ hv,
    float* __restrict__ hg)
{
    const int z = blockIdx.z;
    const unsigned short* A = z == 0 ? xw : z == 1 ? xa : z == 2 ? xv : xg;
    const unsigned short* W = lw16 + (size_t)(z == 0 ? 0 : z == 1 ? 64 : z == 2 ? 128 : 192) * 1024;
    float* out = z == 0 ? hw : z == 1 ? ha : z == 2 ? hv : hg;
    const int N  = z == 3 ? 128 : z == 2 ? 32 : 64;
    const int Ns = z == 3 ? 128 : 64;
    const int n0 = blockIdx.x * 64;
    if (n0 >= Ns) return;

    __shared__ unsigned short Ab[2][128 * 32];
    __shared__ unsigned short Bb[2][64 * 32];
    const int tid = threadIdx.x;
    const int lane = tid & 63;
    const int w = tid >> 6;
    const int t0 = blockIdx.y * 128;
    const int wm = (w & 1) * 64;
    const int wn = (w >> 1) * 32;
    const int srow = lane >> 2;
    const int scol = (lane & 3) * 8;

    f4_t acc[4][2];
#pragma unroll
    for (int i = 0; i < 4; ++i)
#pragma unroll
        for (int j = 0; j < 2; ++j)
            acc[i][j] = (f4_t){0.f, 0.f, 0.f, 0.f};

#pragma unroll
    for (int s = 0; s < 2; ++s) {
        const int i = 2 * w + s;
        __builtin_amdgcn_global_load_lds(
            (const AS1 unsigned int*)(A + (size_t)(t0 + i * 16 + srow) * 1024 + scol),
            (AS3 unsigned int*)(&Ab[0][i * 512 + lane * 8]), 16, 0, 0);
    }
    __builtin_amdgcn_global_load_lds(
        (const AS1 unsigned int*)(W + (size_t)(n0 + w * 16 + srow) * 1024 + scol),
        (AS3 unsigned int*)(&Bb[0][w * 512 + lane * 8]), 16, 0, 0);

    const int mrow = lane & 15;
    const int kq = (lane >> 4) * 8;
    for (int k0 = 0; k0 < 1024; k0 += 32) {
        const int cur = (k0 >> 5) & 1, nxt = cur ^ 1;
        __syncthreads();
        if (k0 + 32 < 1024) {
            const int k1 = k0 + 32;
#pragma unroll
            for (int s = 0; s < 2; ++s) {
                const int i = 2 * w + s;
                __builtin_amdgcn_global_load_lds(
                    (const AS1 unsigned int*)(A + (size_t)(t0 + i * 16 + srow) * 1024 + k1 + scol),
                    (AS3 unsigned int*)(&Ab[nxt][i * 512 + lane * 8]), 16, 0, 0);
            }
            __builtin_amdgcn_global_load_lds(
                (const AS1 unsigned int*)(W + (size_t)(n0 + w * 16 + srow) * 1024 + k1 + scol),
                (AS3 unsigned int*)(&Bb[nxt][w * 512 + lane * 8]), 16, 0, 0);
        }
        bf8_t af[4], bfr[2];
#pragma unroll
        for (int i = 0; i < 4; ++i)
            af[i] = *(const bf8_t*)(&Ab[cur][(wm + 16 * i + mrow) * 32 + kq]);
#pragma unroll
        for (int j = 0; j < 2; ++j)
            bfr[j] = *(const bf8_t*)(&Bb[cur][(wn + 16 * j + mrow) * 32 + kq]);
#pragma unroll
        for (int i = 0; i < 4; ++i)
#pragma unroll
            for (int j = 0; j < 2; ++j)
                acc[i][j] = __builtin_amdgcn_mfma_f32_16x16x32_bf16(
                    af[i], bfr[j], acc[i][j], 0, 0, 0);
    }
    const int crow = (lane >> 4) * 4;
    const int ccol = lane & 15;
#pragma unroll
    for (int i = 0; i < 4; ++i)
#pragma unroll
        for (int j = 0; j < 2; ++j) {
            const int col = n0 + wn + 16 * j + ccol;
            if (col < N) {
#pragma unroll
                for (int u = 0; u < 4; ++u) {
                    float vv = acc[i][j][u];
                    if (z == 0) vv = tanhf(vv);
                    else if (z == 3) vv = sigf(vv);
                    out[(size_t)(t0 + wm + 16 * i + crow + u) * N + col] = vv;
                }
            }
        }
}

// ---------------------------------------------------------------------------
// Fused LoRA-2 (w/a/v/g) + k post-process + PAIR-COMPOSED packet packing.
// Block = 16 tokens x 256 channels; head = 64 consecutive channels = 1 wave.
// Per step-pair packet (768 floats):
//   E=e1e2 @0 | A1=aa1 @64 | A2e=e1*aa2 @128 | B1e=bb1*e2 @192 | K1e=k1*e2 @256
//   | B2=bb2 @320 | K2=k2 @384 | R1e=e1*r1 @448 | R2e=E*r2 @512
//   | vv interleaved @576: {v1,v2} per channel (128 floats)
//   | scalars @704: cba=bb1.aa2, cka=k1.aa2, cbr=bb1.r1, ckr=k1.r1
//   | scalars @708: cbr2=B1e.r2, ckr2=K1e.r2, cb2r2=bb2.r2, ck2r2=k2.r2
// ---------------------------------------------------------------------------
__global__ __launch_bounds__(256) void lora2f(
    const float* __restrict__ hwB, const float* __restrict__ haB,
    const float* __restrict__ hvB, const float* __restrict__ hgB,
    const float* __restrict__ w2, const float* __restrict__ a2,
    const float* __restrict__ v2, const float* __restrict__ g2,
    const float* __restrict__ w0, const float* __restrict__ a0,
    const float* __restrict__ v0,
    const float* __restrict__ k_k, const float* __restrict__ k_a,
    const float* __restrict__ v_first, const float* __restrict__ rB,
    float* __restrict__ kB, float* __restrict__ vB, float* __restrict__ gB,
    float* __restrict__ pk)
{
    __shared__ __align__(16) float hsW[16 * 64], hsA[16 * 64];
    __shared__ __align__(16) float hsV[16 * 32], hsG[16 * 128];
    const int tid = threadIdx.x;
    const int t0 = blockIdx.y * 16;
    const int i  = blockIdx.x * 256 + tid;
    const int h  = i >> 6;
    const int j  = i & 63;
    for (int idx = tid; idx < 16 * 64; idx += 256) {
        hsW[idx] = hwB[(size_t)t0 * 64 + idx];
        hsA[idx] = haB[(size_t)t0 * 64 + idx];
    }
    for (int idx = tid; idx < 16 * 32; idx += 256)
        hsV[idx] = hvB[(size_t)t0 * 32 + idx];
    for (int idx = tid; idx < 16 * 128; idx += 256)
        hsG[idx] = hgB[(size_t)t0 * 128 + idx];
    __syncthreads();

    float av[16], ew[16], vf[16];
    { // a = sigmoid(a0 + ha@a2)
        float acc[16];
        const float b0 = a0[i];
#pragma unroll
        for (int tt = 0; tt < 16; ++tt) acc[tt] = b0;
        for (int jj = 0; jj < 64; jj += 4) {
            const float q0 = a2[(size_t)(jj + 0) * C_DIM + i];
            const float q1 = a2[(size_t)(jj + 1) * C_DIM + i];
            const float q2 = a2[(size_t)(jj + 2) * C_DIM + i];
            const float q3 = a2[(size_t)(jj + 3) * C_DIM + i];
#pragma unroll
            for (int tt = 0; tt < 16; ++tt) {
                float4 h4 = *(const float4*)(hsA + tt * 64 + jj);
                acc[tt] = fmaf(h4.x, q0, acc[tt]);
                acc[tt] = fmaf(h4.y, q1, acc[tt]);
                acc[tt] = fmaf(h4.z, q2, acc[tt]);
                acc[tt] = fmaf(h4.w, q3, acc[tt]);
            }
        }
#pragma unroll
        for (int tt = 0; tt < 16; ++tt) av[tt] = sigf(acc[tt]);
    }
    { // exp(w)
        float acc[16];
        const float b0 = w0[i];
#pragma unroll
        for (int tt = 0; tt < 16; ++tt) acc[tt] = b0;
        for (int jj = 0; jj < 64; jj += 4) {
            const float q0 = w2[(size_t)(jj + 0) * C_DIM + i];
            const float q1 = w2[(size_t)(jj + 1) * C_DIM + i];
            const float q2 = w2[(size_t)(jj + 2) * C_DIM + i];
            const float q3 = w2[(size_t)(jj + 3) * C_DIM + i];
#pragma unroll
            for (int tt = 0; tt < 16; ++tt) {
                float4 h4 = *(const float4*)(hsW + tt * 64 + jj);
                acc[tt] = fmaf(h4.x, q0, acc[tt]);
                acc[tt] = fmaf(h4.y, q1, acc[tt]);
                acc[tt] = fmaf(h4.z, q2, acc[tt]);
                acc[tt] = fmaf(h4.w, q3, acc[tt]);
            }
        }
#pragma unroll
        for (int tt = 0; tt < 16; ++tt)
            ew[tt] = __expf(-0.6065306597126334f * sigf(acc[tt]));
    }
    { // v mix
        float acc[16];
        const float b0 = v0[i];
#pragma unroll
        for (int tt = 0; tt < 16; ++tt) acc[tt] = b0;
        for (int jj = 0; jj < 32; jj += 4) {
            const float q0 = v2[(size_t)(jj + 0) * C_DIM + i];
            const float q1 = v2[(size_t)(jj + 1) * C_DIM + i];
            const float q2 = v2[(size_t)(jj + 2) * C_DIM + i];
            const float q3 = v2[(size_t)(jj + 3) * C_DIM + i];
#pragma unroll
            for (int tt = 0; tt < 16; ++tt) {
                float4 h4 = *(const float4*)(hsV + tt * 32 + jj);
                acc[tt] = fmaf(h4.x, q0, acc[tt]);
                acc[tt] = fmaf(h4.y, q1, acc[tt]);
                acc[tt] = fmaf(h4.z, q2, acc[tt]);
                acc[tt] = fmaf(h4.w, q3, acc[tt]);
            }
        }
#pragma unroll
        for (int tt = 0; tt < 16; ++tt) {
            const size_t gi = (size_t)(t0 + tt) * C_DIM + i;
            const float s = sigf(acc[tt]);
            const float vr = vB[gi];
            vf[tt] = vr + (v_first[gi] - vr) * s;
            vB[gi] = vf[tt];
        }
    }
    { // g
        float acc[16];
#pragma unroll
        for (int tt = 0; tt < 16; ++tt) acc[tt] = 0.f;
        for (int jj = 0; jj < 128; jj += 4) {
            const float q0 = g2[(size_t)(jj + 0) * C_DIM + i];
            const float q1 = g2[(size_t)(jj + 1) * C_DIM + i];
            const float q2 = g2[(size_t)(jj + 2) * C_DIM + i];
            const float q3 = g2[(size_t)(jj + 3) * C_DIM + i];
#pragma unroll
            for (int tt = 0; tt < 16; ++tt) {
                float4 h4 = *(const float4*)(hsG + tt * 128 + jj);
                acc[tt] = fmaf(h4.x, q0, acc[tt]);
                acc[tt] = fmaf(h4.y, q1, acc[tt]);
                acc[tt] = fmaf(h4.z, q2, acc[tt]);
                acc[tt] = fmaf(h4.w, q3, acc[tt]);
            }
        }
#pragma unroll
        for (int tt = 0; tt < 16; ++tt)
            gB[(size_t)(t0 + tt) * C_DIM + i] = acc[tt];
    }
    // k post-process + pair-composed packing
    const float kkw = k_k[i], kaw = k_a[i];
    const size_t pbase = (size_t)h * 1024 * PAIR_F;
    for (int pt = 0; pt < 8; ++pt) {
        float r_[2], e_[2], kf_[2], v_[2], aa_[2], bb_[2];
#pragma unroll
        for (int u = 0; u < 2; ++u) {
            const int tt = 2 * pt + u;
            const size_t gi = (size_t)(t0 + tt) * C_DIM + i;
            const float kraw = kB[gi];
            const float kn = kraw * kkw;
            float ss = kn * kn;
#pragma unroll
            for (int m = 1; m <= 32; m <<= 1) ss += __shfl_xor(ss, m);
            const float sc = 1.f / fmaxf(sqrtf(ss), 1e-12f);
            const float kk = kn * sc;
            const float a_ = av[tt];
            const float kf = kraw * (1.f + (a_ - 1.f) * kaw);
            kB[gi] = kf;
            r_[u] = rB[gi];
            e_[u] = ew[tt];
            kf_[u] = kf;
            v_[u] = vf[tt];
            aa_[u] = -kk;
            bb_[u] = kk * a_;
        }
        const float E   = e_[0] * e_[1];
        const float A2e = e_[0] * aa_[1];
        const float B1e = bb_[0] * e_[1];
        const float K1e = kf_[0] * e_[1];
        const float R1e = e_[0] * r_[0];
        float cba = bb_[0] * aa_[1];
        float cka = kf_[0] * aa_[1];
        float cbr = bb_[0] * r_[0];
        float ckr = kf_[0] * r_[0];
        // o2-decomposition cross-scalars (dots against R2 = r_[1])
        float cbr2  = B1e * r_[1];
        float ckr2  = K1e * r_[1];
        float cb2r2 = bb_[1] * r_[1];
        float ck2r2 = kf_[1] * r_[1];
#pragma unroll
        for (int m = 1; m <= 32; m <<= 1) {
            cba += __shfl_xor(cba, m);
            cka += __shfl_xor(cka, m);
            cbr += __shfl_xor(cbr, m);
            ckr += __shfl_xor(ckr, m);
            cbr2  += __shfl_xor(cbr2, m);
            ckr2  += __shfl_xor(ckr2, m);
            cb2r2 += __shfl_xor(cb2r2, m);
            ck2r2 += __shfl_xor(ck2r2, m);
        }
        float* p = pk + pbase + (size_t)(blockIdx.y * 8 + pt) * PAIR_F;
        p[j]        = E;
        p[64 + j]   = aa_[0];
        p[128 + j]  = A2e;
        p[192 + j]  = B1e;
        p[256 + j]  = K1e;
        p[320 + j]  = bb_[1];
        p[384 + j]  = kf_[1];
        p[448 + j]  = R1e;
        p[512 + j]  = E * r_[1];          // R2e = E ⊙ R2 (vscan o2 partial)
        p[576 + 2 * j]     = v_[0];       // vv interleaved: one b64 read
        p[576 + 2 * j + 1] = v_[1];
        if (j == 0) {
            p[704] = cba;  p[705] = cka;  p[706] = cbr;  p[707] = ckr;
            p[708] = cbr2; p[709] = ckr2; p[710] = cb2r2; p[711] = ck2r2;
        }
    }
}

// ---------------------------------------------------------------------------
// v-row-parallel scan over step-PAIRS — REGISTER-DIRECT, NO LDS.
// Every packet float is read exactly once per wave -> LDS staging was pure
// overhead (13 ds_read/pair ≈ 150cy of LDS-pipe + lgkm waits). Now: 4-slot
// VGPR ring, global->reg loads 4 pairs ahead (~1200cy > ~900cy HBM miss),
// compiler's precise per-register vmcnt scoreboard replaces all fences.
// Slots are named structs, statically indexed (rule #20: no scratch).
// ---------------------------------------------------------------------------
struct PairV {
    float4 E, A1, A2e, B1e, K1e, B2, K2, R1e, R2e;
    f2_t vv;       // {v1, v2}
    float4 sc;     // cba, cka, cbr, ckr
    float4 sc2;    // cbr2, ckr2, cb2r2, ck2r2
};

static __device__ __forceinline__ float red16(float x) {
    int xi;
    xi = __builtin_amdgcn_mov_dpp(__float_as_int(x), 0x128, 0xf, 0xf, true);
    x += __int_as_float(xi);
    xi = __builtin_amdgcn_mov_dpp(__float_as_int(x), 0x124, 0xf, 0xf, true);
    x += __int_as_float(xi);
    xi = __builtin_amdgcn_mov_dpp(__float_as_int(x), 0x122, 0xf, 0xf, true);
    x += __int_as_float(xi);
    xi = __builtin_amdgcn_mov_dpp(__float_as_int(x), 0x121, 0xf, 0xf, true);
    x += __int_as_float(xi);
    return x;
}

static __device__ __forceinline__ f2_t f2bc(float s) { return (f2_t){s, s}; }
static __device__ __forceinline__ f2_t fma2(f2_t a, f2_t b, f2_t c) {
    return __builtin_elementwise_fma(a, b, c);
}
static __device__ __forceinline__ f2_t lo2(const float4& v) { return (f2_t){v.x, v.y}; }
static __device__ __forceinline__ f2_t hi2(const float4& v) { return (f2_t){v.z, v.w}; }

static __device__ __forceinline__ float dot4pk(f2_t Sl, f2_t Sh, const float4& A) {
    f2_t m = Sl * lo2(A);
    m = fma2(Sh, hi2(A), m);
    return m.x + m.y;
}

static __device__ __forceinline__ void slot_load(
    PairV& P, const float* __restrict__ p, int j0, int vidx)
{
    P.E   = *(const float4*)(p + j0);
    P.A1  = *(const float4*)(p + 64 + j0);
    P.A2e = *(const float4*)(p + 128 + j0);
    P.B1e = *(const float4*)(p + 192 + j0);
    P.K1e = *(const float4*)(p + 256 + j0);
    P.B2  = *(const float4*)(p + 320 + j0);
    P.K2  = *(const float4*)(p + 384 + j0);
    P.R1e = *(const float4*)(p + 448 + j0);
    P.R2e = *(const float4*)(p + 512 + j0);
    P.vv  = *(const f2_t*)(p + 576 + 2 * vidx);
    P.sc  = *(const float4*)(p + 704);
    P.sc2 = *(const float4*)(p + 708);
}

static __device__ __forceinline__ void pair_compute(
    f2_t& Sl, f2_t& Sh, const PairV& P, float& o1o, float& o2o)
{
    // FOUR independent reductions, all from S_old (o2 via R2e + cross-scalars)
    const float u1 = red16(dot4pk(Sl, Sh, P.A1));
    const float u2 = red16(dot4pk(Sl, Sh, P.A2e));
    float o1       = red16(dot4pk(Sl, Sh, P.R1e));
    const float oz = red16(dot4pk(Sl, Sh, P.R2e));

    const float sa1 = u1;
    const float sa2 = fmaf(P.vv.x, P.sc.y, fmaf(sa1, P.sc.x, u2));
    o1 = fmaf(P.vv.x, P.sc.w, fmaf(sa1, P.sc.z, o1));
    const float o2 = fmaf(P.vv.y, P.sc2.w, fmaf(sa2, P.sc2.z,
                     fmaf(P.vv.x, P.sc2.y, fmaf(sa1, P.sc2.x, oz))));
    o1o = o1; o2o = o2;
    // S = S*E + sa1*B1e + v1*K1e + sa2*B2 + v2*K2  (packed FP32, 2 halves)
    const f2_t sa1v = f2bc(sa1), sa2v = f2bc(sa2);
    const f2_t v1v = f2bc(P.vv.x), v2v = f2bc(P.vv.y);
    f2_t nl = Sl * lo2(P.E);
    f2_t nh = Sh * hi2(P.E);
    nl = fma2(sa1v, lo2(P.B1e), nl);
    nh = fma2(sa1v, hi2(P.B1e), nh);
    nl = fma2(v1v, lo2(P.K1e), nl);
    nh = fma2(v1v, hi2(P.K1e), nh);
    nl = fma2(sa2v, lo2(P.B2), nl);
    nh = fma2(sa2v, hi2(P.B2), nh);
    nl = fma2(v2v, lo2(P.K2), nl);
    nh = fma2(v2v, hi2(P.K2), nh);
    Sl = nl; Sh = nh;
}

__global__ __launch_bounds__(64, 1) void vscan(
    const float* __restrict__ pk, const float* __restrict__ init_state,
    float* __restrict__ y)
{
    const int h  = blockIdx.x & 15;     // b%8 == h%8 -> per-head XCD locality
    const int wv = blockIdx.x >> 4;
    const int l  = threadIdx.x;
    const int vidx = wv * 4 + (l >> 4);
    const int j0 = (l & 15) * 4;
    const int cb = h * 64;
    const float* hbase = pk + (size_t)h * 1024 * PAIR_F;

    float4 S4 = *(const float4*)(init_state + h * 4096 + vidx * 64 + j0);
    f2_t Sl = {S4.x, S4.y};
    f2_t Sh = {S4.z, S4.w};

    PairV s0, s1, s2, s3;
    slot_load(s0, hbase + 0 * PAIR_F, j0, vidx);
    slot_load(s1, hbase + 1 * PAIR_F, j0, vidx);
    slot_load(s2, hbase + 2 * PAIR_F, j0, vidx);
    slot_load(s3, hbase + 3 * PAIR_F, j0, vidx);

    const bool wr = (l & 15) == 0;
    float o0, o1, o2, o3, o4, o5, o6, o7;
    // main: 255 iterations x 4 pairs; loads prefetch pairs i+4..i+7
    for (int i = 0; i < 1020; i += 4) {
        const float* pl = hbase + (size_t)(i + 4) * PAIR_F;
        pair_compute(Sl, Sh, s0, o0, o1);
        slot_load(s0, pl + 0 * PAIR_F, j0, vidx);
        pair_compute(Sl, Sh, s1, o2, o3);
        slot_load(s1, pl + 1 * PAIR_F, j0, vidx);
        pair_compute(Sl, Sh, s2, o4, o5);
        slot_load(s2, pl + 2 * PAIR_F, j0, vidx);
        pair_compute(Sl, Sh, s3, o6, o7);
        slot_load(s3, pl + 3 * PAIR_F, j0, vidx);
        if (wr) {
            float* yp = y + (size_t)(2 * i) * C_DIM + cb + vidx;
            yp[0]    = o0; yp[1024] = o1; yp[2048] = o2; yp[3072] = o3;
            yp[4096] = o4; yp[5120] = o5; yp[6144] = o6; yp[7168] = o7;
        }
    }
    // tail: pairs 1020..1023 (no further loads)
    pair_compute(Sl, Sh, s0, o0, o1);
    pair_compute(Sl, Sh, s1, o2, o3);
    pair_compute(Sl, Sh, s2, o4, o5);
    pair_compute(Sl, Sh, s3, o6, o7);
    if (wr) {
        float* yp = y + (size_t)2040 * C_DIM + cb + vidx;
        yp[0]    = o0; yp[1024] = o1; yp[2048] = o2; yp[3072] = o3;
        yp[4096] = o4; yp[5120] = o5; yp[6144] = o6; yp[7168] = o7;
    }
}

// ---------------------------------------------------------------------------
// GroupNorm + bonus + *g ; writes bf16 (xo*g) for the final MFMA GEMM.
// ---------------------------------------------------------------------------
__global__ __launch_bounds__(256) void gn_bonus(
    const float* __restrict__ y, const float* __restrict__ rb,
    const float* __restrict__ kb, const float* __restrict__ vb,
    const float* __restrict__ gb, const float* __restrict__ r_k,
    const float* __restrict__ lnw, const float* __restrict__ lnb,
    unsigned short* __restrict__ yg)
{
    const int t = blockIdx.x, tid = threadIdx.x;
    const int c0 = tid << 2;
    const size_t base = (size_t)t * C_DIM + c0;
    float4 yv = *(const float4*)(y + base);
    float sum = yv.x + yv.y + yv.z + yv.w;
    float ss  = yv.x * yv.x + yv.y * yv.y + yv.z * yv.z + yv.w * yv.w;
    float4 rv = *(const float4*)(rb + base);
    float4 kv = *(const float4*)(kb + base);
    float4 rkv = *(const float4*)(r_k + c0);
    float dot = rv.x * kv.x * rkv.x + rv.y * kv.y * rkv.y +
                rv.z * kv.z * rkv.z + rv.w * kv.w * rkv.w;
#pragma unroll
    for (int m = 1; m <= 8; m <<= 1) {
        sum += __shfl_xor(sum, m);
        ss  += __shfl_xor(ss, m);
        dot += __shfl_xor(dot, m);
    }
    const float mu = sum * 0.015625f;
    const float var = ss * 0.015625f - mu * mu;
    const float rstd = rsqrtf(var + 0.00064f);
    float4 wv = *(const float4*)(lnw + c0);
    float4 bv = *(const float4*)(lnb + c0);
    float4 vv = *(const float4*)(vb + base);
    float4 gv = *(const float4*)(gb + base);
    ushort4 o;
    o.x = f2bf(((yv.x - mu) * rstd * wv.x + bv.x + dot * vv.x) * gv.x);
    o.y = f2bf(((yv.y - mu) * rstd * wv.y + bv.y + dot * vv.y) * gv.y);
    o.z = f2bf(((yv.z - mu) * rstd * wv.z + bv.z + dot * vv.z) * gv.z);
    o.w = f2bf(((yv.w - mu) * rstd * wv.w + bv.w + dot * vv.w) * gv.w);
    *(ushort4*)(yg + base) = o;
}

// ---------------------------------------------------------------------------
extern "C" void kernel_launch(void* const* d_in, const int* in_sizes, int n_in,
                              void* d_out, int out_size, void* d_ws, size_t ws_size,
                              hipStream_t stream)
{
    (void)in_sizes; (void)n_in; (void)out_size; (void)ws_size;
    const float* x       = (const float*)d_in[0];
    const float* v_first = (const float*)d_in[1];
    const float* x_prev  = (const float*)d_in[2];
    const float* init_st = (const float*)d_in[3];
    const float* x_r = (const float*)d_in[4];
    const float* x_w = (const float*)d_in[5];
    const float* x_k = (const float*)d_in[6];
    const float* x_v = (const float*)d_in[7];
    const float* x_a = (const float*)d_in[8];
    const float* x_g = (const float*)d_in[9];
    const float* w0  = (const float*)d_in[10];
    const float* a0  = (const float*)d_in[11];
    const float* v0  = (const float*)d_in[12];
    const float* k_k = (const float*)d_in[13];
    const float* k_a = (const float*)d_in[14];
    const float* w1  = (const float*)d_in[15];
    const float* w2  = (const float*)d_in[16];
    const float* a1  = (const float*)d_in[17];
    const float* a2  = (const float*)d_in[18];
    const float* v1  = (const float*)d_in[19];
    const float* v2  = (const float*)d_in[20];
    const float* g1  = (const float*)d_in[21];
    const float* g2  = (const float*)d_in[22];
    const float* r_k = (const float*)d_in[23];
    const float* Wr  = (const float*)d_in[24];
    const float* Wk  = (const float*)d_in[25];
    const float* Wv  = (const float*)d_in[26];
    const float* Wo  = (const float*)d_in[27];
    const float* ln_w = (const float*)d_in[28];
    const float* ln_b = (const float*)d_in[29];

    float* out = (float*)d_out;
    float* ws  = (float*)d_ws;
    const size_t NE = (size_t)T_LEN * C_DIM;   // 2M
    const size_t WE = (size_t)C_DIM * C_DIM;   // 1M
    float* rB  = ws;
    float* kB  = ws + NE;
    float* vB  = ws + 2 * NE;
    float* gB  = ws + 3 * NE;
    float* hwB = ws + 4 * NE;                  // T*64
    float* haB = hwB + (size_t)T_LEN * 64;
    float* hvB = haB + (size_t)T_LEN * 64;
    float* hgB = hvB + (size_t)T_LEN * 32;     // h region < NE/2
    float* pk  = ws + 4 * NE + NE / 2;         // 6*NE floats (16*1024*768)
    unsigned short* b16 = (unsigned short*)(ws + 10 * NE + NE / 2);
    unsigned short* xr16 = b16;                // NE shorts
    unsigned short* xk16 = b16 + NE;
    unsigned short* xv16 = b16 + 2 * NE;
    unsigned short* Wr16 = b16 + 3 * NE;       // 4*WE shorts
    unsigned short* Wk16 = Wr16 + WE;
    unsigned short* Wv16 = Wr16 + 2 * WE;
    unsigned short* Wo16 = Wr16 + 3 * WE;
    unsigned short* yg16 = b16 + 3 * NE + 4 * WE;  // NE shorts
    unsigned short* lw16 = yg16 + NE;              // 320K shorts (LoRA weights)
    // xw/xa/xg bf16 live in the pk region (pk written later by lora2f)
    unsigned short* xw16 = (unsigned short*)pk;
    unsigned short* xa16 = xw16 + NE;
    unsigned short* xg16 = xw16 + 2 * NE;
    // yB aliases xr16/xk16 (consumed by gemms before vscan writes it)
    float* yB = (float*)xr16;

    wcvtall<<<4384, 256, 0, stream>>>(Wr, Wk, Wv, Wo, w1, a1, v1, g1,
                                      Wr16, lw16);
    xcvt<<<T_LEN, 256, 0, stream>>>(x, x_prev, x_r, x_k, x_v, x_w, x_a, x_g,
                                    xr16, xk16, xv16, xw16, xa16, xg16);

    gemm_bf16_3<<<dim3(16, 16, 3), 256, 0, stream>>>(
        xr16, xk16, xv16, Wr16, Wk16, Wv16, rB, kB, vB);

    lora1m<<<dim3(2, 16, 4), 256, 0, stream>>>(
        xw16, xa16, xv16, xg16, lw16, hwB, haB, hvB, hgB);

    lora2f<<<dim3(4, 128), 256, 0, stream>>>(
        hwB, haB, hvB, hgB, w2, a2, v2, g2, w0, a0, v0,
        k_k, k_a, v_first, rB, kB, vB, gB, pk);

    vscan<<<256, 64, 0, stream>>>(pk, init_st, yB);
    gn_bonus<<<T_LEN, 256, 0, stream>>>(yB, rB, kB, vB, gB, r_k, ln_w, ln_b, yg16);
    gemm_bf16<<<dim3(16, 16), 256, 0, stream>>>(yg16, Wo16, out);
}